// Round 13
// baseline (313.997 us; speedup 1.0000x reference)
//
#include <hip/hip_runtime.h>
#include <hip/hip_bf16.h>
#include <math.h>

#define NN 384
#define HD 768
#define EE 12288
#define NCHUNK (EE / 256)
#define NEXPERT 8
#define TOPK 2
#define NLAYER 3
#define NHEADS 4
#define NMASK 38
#define GATB 3136   // GAT B rows: 3072 weight cols + 8 el/er rows + 56 pad

typedef __attribute__((ext_vector_type(8))) short short8v;
typedef __attribute__((ext_vector_type(4))) float f32x4;
typedef __attribute__((ext_vector_type(2))) float f32x2;
typedef __attribute__((ext_vector_type(4))) int int4v;

__device__ __forceinline__ float gelu_f(float x) {
    return x * 0.5f * (1.f + erff(x * 0.70710678118654752440f));
}

__device__ __forceinline__ ushort f2bf(float x) {
    unsigned u = __float_as_uint(x);
    u += 0x7fffu + ((u >> 16) & 1u);
    return (ushort)(u >> 16);
}

// ---------------------------------------------------------------- fused xm+gate (+edge hist)
__global__ __launch_bounds__(256) void k_xm_gate_hist(const float* __restrict__ a,
        const float* __restrict__ b, const int* __restrict__ mask_idx,
        const float* __restrict__ mt, ushort* __restrict__ xm_bf,
        const float* __restrict__ gW, const float* __restrict__ gb,
        int* __restrict__ topi, float* __restrict__ topw,
        const int* __restrict__ dst, int* __restrict__ counts) {
    if (blockIdx.x >= NN) {
        __shared__ int h[NN];
        int c = blockIdx.x - NN;
        for (int i = threadIdx.x; i < NN; i += 256) h[i] = 0;
        __syncthreads();
        atomicAdd(&h[dst[c * 256 + threadIdx.x]], 1);
        __syncthreads();
        for (int i = threadIdx.x; i < NN; i += 256) counts[c * NN + i] = h[i];
        return;
    }
    int n = blockIdx.x, tid = threadIdx.x;
    __shared__ float xs[HD];
    __shared__ int ism;
    __shared__ float logits[NEXPERT];
    if (tid == 0) ism = 0;
    __syncthreads();
    if (tid < NMASK && mask_idx[tid] == n) ism = 1;
    __syncthreads();
#pragma unroll
    for (int r = 0; r < 3; r++) {
        int j = r * 256 + tid;
        float v = ism ? mt[j] : 0.5f * (a[(size_t)n * HD + j] + b[(size_t)n * HD + j]);
        xs[j] = v;
        xm_bf[(size_t)n * HD + j] = f2bf(v);
    }
    __syncthreads();
    int grp = tid >> 5;
    int l32 = tid & 31;
    float p = 0.f;
    for (int dd = l32; dd < HD; dd += 32) p += xs[dd] * gW[dd * NEXPERT + grp];
#pragma unroll
    for (int m = 1; m < 32; m <<= 1) p += __shfl_xor(p, m, 32);
    if (l32 == 0) logits[grp] = p + gb[grp];
    __syncthreads();
    if (tid == 0) {
        float mx = logits[0];
#pragma unroll
        for (int e = 1; e < NEXPERT; e++) mx = fmaxf(mx, logits[e]);
        float sm[NEXPERT]; float s = 0.f;
#pragma unroll
        for (int e = 0; e < NEXPERT; e++) { sm[e] = expf(logits[e] - mx); s += sm[e]; }
#pragma unroll
        for (int e = 0; e < NEXPERT; e++) sm[e] /= s;
        int i0 = 0; float b0 = sm[0];
#pragma unroll
        for (int e = 1; e < NEXPERT; e++) if (sm[e] > b0) { b0 = sm[e]; i0 = e; }
        int i1 = -1; float b1v = -1.f;
#pragma unroll
        for (int e = 0; e < NEXPERT; e++) if (e != i0 && sm[e] > b1v) { b1v = sm[e]; i1 = e; }
        float ssum = b0 + b1v;
        topi[n * 2] = i0; topi[n * 2 + 1] = i1;
        topw[n * 2] = b0 / ssum; topw[n * 2 + 1] = b1v / ssum;
    }
}

// ---------------------------------------------------------------- all weight transposes (+Wal/War rows)
__global__ __launch_bounds__(256) void k_transpose_all(
        const float* __restrict__ w1, const float* __restrict__ w2,
        const float* __restrict__ gw, const float* __restrict__ sw,
        const float* __restrict__ dw1, const float* __restrict__ dw2,
        ushort* __restrict__ o1, ushort* __restrict__ o2, ushort* __restrict__ og,
        ushort* __restrict__ os, ushort* __restrict__ od1, ushort* __restrict__ od2,
        const float* __restrict__ gal, const float* __restrict__ gar) {
    __shared__ float smem[8448];
    int b = blockIdx.x;
    int tid = threadIdx.x;
    if (b >= 9792) {
        // el/er projection rows: ext[l][3072+ri][k] = sum_j gw_l[k][(ri&3)*768+j]*a[ri][j]
        int b2 = b - 9792;          // 0..35
        int l = b2 / 12, kc = b2 % 12;
        float* aLDS = smem;          // [8][768]
        float* red = smem + 6144;    // [4][64][8]
        for (int idx = tid; idx < 8 * HD; idx += 256) {
            int ri = idx / HD, j = idx - ri * HD;
            aLDS[idx] = (ri < 4) ? gal[((size_t)l * 4 + ri) * HD + j]
                                 : gar[((size_t)l * 4 + (ri - 4)) * HD + j];
        }
        __syncthreads();
        int q = tid >> 6, kk = tid & 63;
        int k = kc * 64 + kk;
        const float* wrow = gw + ((size_t)l * HD + k) * (4 * HD);
        float acc[8] = {};
        for (int j = q * 192; j < q * 192 + 192; j++) {
            float w0 = wrow[0 * HD + j], w1v = wrow[1 * HD + j];
            float w2v = wrow[2 * HD + j], w3 = wrow[3 * HD + j];
            acc[0] += w0 * aLDS[0 * HD + j]; acc[4] += w0 * aLDS[4 * HD + j];
            acc[1] += w1v * aLDS[1 * HD + j]; acc[5] += w1v * aLDS[5 * HD + j];
            acc[2] += w2v * aLDS[2 * HD + j]; acc[6] += w2v * aLDS[6 * HD + j];
            acc[3] += w3 * aLDS[3 * HD + j]; acc[7] += w3 * aLDS[7 * HD + j];
        }
#pragma unroll
        for (int ri = 0; ri < 8; ri++) red[(q * 64 + kk) * 8 + ri] = acc[ri];
        __syncthreads();
        if (tid < 64) {
#pragma unroll
            for (int ri = 0; ri < 8; ri++) {
                float s = red[(0 * 64 + tid) * 8 + ri] + red[(1 * 64 + tid) * 8 + ri]
                        + red[(2 * 64 + tid) * 8 + ri] + red[(3 * 64 + tid) * 8 + ri];
                og[(size_t)l * GATB * HD + (size_t)(3072 + ri) * HD + kc * 64 + tid] = f2bf(s);
            }
        }
        return;
    }
    const float* src; ushort* dst; int N, loc, tilesX; size_t outStrideZ;
    if (b < 2304)      { src = w1;  dst = o1;  N = HD;     loc = b;        tilesX = 24; outStrideZ = (size_t)HD * HD; }
    else if (b < 4608) { src = w2;  dst = o2;  N = HD;     loc = b - 2304; tilesX = 24; outStrideZ = (size_t)HD * HD; }
    else if (b < 8064) { src = gw;  dst = og;  N = 4 * HD; loc = b - 4608; tilesX = 96; outStrideZ = (size_t)GATB * HD; }
    else if (b < 8640) { src = sw;  dst = os;  N = HD;     loc = b - 8064; tilesX = 24; outStrideZ = (size_t)HD * HD; }
    else if (b < 9216) { src = dw1; dst = od1; N = HD;     loc = b - 8640; tilesX = 24; outStrideZ = (size_t)HD * HD; }
    else               { src = dw2; dst = od2; N = HD;     loc = b - 9216; tilesX = 24; outStrideZ = (size_t)HD * HD; }
    const int K = HD;
    int tilesPerZ = tilesX * 12;
    int z = loc / tilesPerZ;
    int rem = loc - z * tilesPerZ;
    int ty = rem / tilesX, tx = rem - ty * tilesX;
    const float* inz = src + (size_t)z * K * N;
    ushort* outz = dst + (size_t)z * outStrideZ;
    int n0 = tx * 32, k0 = ty * 64;

    float (*t)[33] = reinterpret_cast<float (*)[33]>(smem);
    int r = tid >> 2, c8 = (tid & 3) * 8;
    const float* ip = inz + (size_t)(k0 + r) * N + n0 + c8;
    float4 va = *reinterpret_cast<const float4*>(ip);
    float4 vb = *reinterpret_cast<const float4*>(ip + 4);
    t[r][c8 + 0] = va.x; t[r][c8 + 1] = va.y; t[r][c8 + 2] = va.z; t[r][c8 + 3] = va.w;
    t[r][c8 + 4] = vb.x; t[r][c8 + 5] = vb.y; t[r][c8 + 6] = vb.z; t[r][c8 + 7] = vb.w;
    __syncthreads();
    int nn = tid >> 3;
    int kk = (tid & 7) * 8;
    uint4 o;
    uint pk[4];
#pragma unroll
    for (int q = 0; q < 4; q++) {
        ushort lo = f2bf(t[kk + 2 * q][nn]);
        ushort hi = f2bf(t[kk + 2 * q + 1][nn]);
        pk[q] = (uint)lo | ((uint)hi << 16);
    }
    o.x = pk[0]; o.y = pk[1]; o.z = pk[2]; o.w = pk[3];
    *reinterpret_cast<uint4*>(outz + (size_t)(n0 + nn) * K + k0 + kk) = o;
}

// ---------------------------------------------------------------- fused scan (edges) + MoE meta
__global__ __launch_bounds__(NN) void k_scan_meta(const int* __restrict__ counts,
        int* __restrict__ chunkbase, int* __restrict__ nstart,
        const int* __restrict__ topi, int* __restrict__ ecnt, int* __restrict__ estart,
        int* __restrict__ posArr, int* __restrict__ eofpos, int* __restrict__ rowlist,
        int* __restrict__ dec_rs) {
    int tid = threadIdx.x;
    if (blockIdx.x == 0) {
        __shared__ int tot[NN];
        int n = tid;
        int s = 0;
        for (int c = 0; c < NCHUNK; c++) { chunkbase[c * NN + n] = s; s += counts[c * NN + n]; }
        tot[n] = s;
        __syncthreads();
        for (int off = 1; off < NN; off <<= 1) {
            int v = tot[n];
            int add = (n >= off) ? tot[n - off] : 0;
            __syncthreads();
            tot[n] = v + add;
            __syncthreads();
        }
        nstart[n + 1] = tot[n];
        if (n == 0) nstart[0] = 0;
        return;
    }
    __shared__ int ti[NN * TOPK];
    __shared__ int cnt[NEXPERT];
    __shared__ int est[NEXPERT + 1];
    if (tid < NEXPERT) cnt[tid] = 0;
    __syncthreads();
    for (int a = tid; a < NN * TOPK; a += NN) ti[a] = topi[a];
    __syncthreads();
    for (int a = tid; a < NN * TOPK; a += NN) atomicAdd(&cnt[ti[a]], 1);
    __syncthreads();
    if (tid == 0) {
        int s = 0;
        for (int e = 0; e < NEXPERT; e++) { est[e] = s; s += cnt[e]; }
        est[NEXPERT] = s;
        dec_rs[0] = 0; dec_rs[1] = NMASK;
    }
    __syncthreads();
    if (tid < NEXPERT) { ecnt[tid] = cnt[tid]; estart[tid] = est[tid]; }
    if (tid == 0) estart[NEXPERT] = est[NEXPERT];
    for (int a = tid; a < NN * TOPK; a += NN) {
        int e = ti[a]; int rank = 0;
        for (int a2 = 0; a2 < a; a2++) rank += (ti[a2] == e) ? 1 : 0;
        int p = est[e] + rank;
        posArr[a] = p; eofpos[p] = e; rowlist[p] = a >> 1;
    }
}

__global__ __launch_bounds__(256) void k_rank2(const int* __restrict__ dst,
        const int* __restrict__ chunkbase, const int* __restrict__ nstart,
        int* __restrict__ esorted) {
    __shared__ int ds[256];
    int c = blockIdx.x;
    int e = c * 256 + threadIdx.x;
    int d = dst[e];
    ds[threadIdx.x] = d;
    __syncthreads();
    int r = 0;
    for (int i = 0; i < threadIdx.x; i++) r += (ds[i] == d) ? 1 : 0;
    esorted[nstart[d] + chunkbase[c * NN + d] + r] = e;
}

// ---------------------------------------------------------------- bf16 MFMA GEMM (pipelined body)
__device__ __forceinline__ short8v ldfrag(const ushort* s, int r, int kb) {
    int c = kb ^ (r & 7);
    return *reinterpret_cast<const short8v*>(s + r * 64 + c * 8);
}

__device__ __forceinline__ void gemm_body(
        const ushort* __restrict__ A, const ushort* __restrict__ Bt, float* __restrict__ C,
        int M, int Ncol, int K, int lda, int ldc, long strideBt, long strideC,
        const int* __restrict__ rowsA, const int* __restrict__ Ms,
        const int* __restrict__ rowStarts, int z, ushort* Asm, ushort* Bsm) {
    int Meff = Ms ? Ms[z] : M;
    int row0 = blockIdx.y * 64;
    if (row0 >= Meff) return;
    int col0 = blockIdx.x * 64;
    if (col0 >= Ncol) return;
    int rowbase = rowStarts ? rowStarts[z] : 0;
    const ushort* Btz = Bt + (size_t)z * strideBt;
    float* Cz = C + (size_t)rowbase * ldc + (size_t)z * strideC;
    const int* rz = rowsA ? (rowsA + rowbase) : nullptr;

    int tid = threadIdx.x;
    int w = tid >> 6, lane = tid & 63;
    int wr = w >> 1, wc = w & 1;
    int l15 = lane & 15, lq = lane >> 4;

    int r0s = tid >> 3, c0s = tid & 7;
    int cs0 = c0s ^ (r0s & 7);
    int r1s = r0s + 32;
    int cs1 = c0s ^ (r1s & 7);
    int grow0 = row0 + r0s, grow1 = row0 + r1s;
    bool ok0 = grow0 < Meff, ok1 = grow1 < Meff;
    int srow0 = ok0 ? (rz ? rz[grow0] : rowbase + grow0) : (rz ? rz[0] : rowbase);
    int srow1 = ok1 ? (rz ? rz[grow1] : rowbase + grow1) : (rz ? rz[0] : rowbase);
    const ushort* aP0 = A + (size_t)srow0 * lda + c0s * 8;
    const ushort* aP1 = A + (size_t)srow1 * lda + c0s * 8;
    const ushort* bP0 = Btz + (size_t)(col0 + r0s) * K + c0s * 8;
    const ushort* bP1 = Btz + (size_t)(col0 + r1s) * K + c0s * 8;
    ushort* asm0 = &Asm[r0s * 64 + cs0 * 8];
    ushort* asm1 = &Asm[r1s * 64 + cs1 * 8];
    ushort* bsm0 = &Bsm[r0s * 64 + cs0 * 8];
    ushort* bsm1 = &Bsm[r1s * 64 + cs1 * 8];
    const int4v z4 = (int4v){0, 0, 0, 0};

    f32x4 acc[2][2];
#pragma unroll
    for (int i = 0; i < 2; i++)
#pragma unroll
        for (int j = 0; j < 2; j++) acc[i][j] = (f32x4){0.f, 0.f, 0.f, 0.f};

    int4v ta0 = *reinterpret_cast<const int4v*>(aP0);
    int4v ta1 = *reinterpret_cast<const int4v*>(aP1);
    int4v av0 = ok0 ? ta0 : z4;
    int4v av1 = ok1 ? ta1 : z4;
    int4v bv0 = *reinterpret_cast<const int4v*>(bP0);
    int4v bv1 = *reinterpret_cast<const int4v*>(bP1);

    for (int k0 = 0; k0 < K; k0 += 64) {
        *reinterpret_cast<int4v*>(asm0) = av0;
        *reinterpret_cast<int4v*>(asm1) = av1;
        *reinterpret_cast<int4v*>(bsm0) = bv0;
        *reinterpret_cast<int4v*>(bsm1) = bv1;
        __syncthreads();
        int kn = k0 + 64;
        if (kn < K) {
            int4v na0 = *reinterpret_cast<const int4v*>(aP0 + kn);
            int4v na1 = *reinterpret_cast<const int4v*>(aP1 + kn);
            av0 = ok0 ? na0 : z4;
            av1 = ok1 ? na1 : z4;
            bv0 = *reinterpret_cast<const int4v*>(bP0 + kn);
            bv1 = *reinterpret_cast<const int4v*>(bP1 + kn);
        }
#pragma unroll
        for (int ks = 0; ks < 2; ks++) {
            int kb = ks * 4 + lq;
            short8v a0 = ldfrag(Asm, wr * 32 + l15, kb);
            short8v a1 = ldfrag(Asm, wr * 32 + 16 + l15, kb);
            short8v b0 = ldfrag(Bsm, wc * 32 + l15, kb);
            short8v b1 = ldfrag(Bsm, wc * 32 + 16 + l15, kb);
            acc[0][0] = __builtin_amdgcn_mfma_f32_16x16x32_bf16(a0, b0, acc[0][0], 0, 0, 0);
            acc[0][1] = __builtin_amdgcn_mfma_f32_16x16x32_bf16(a0, b1, acc[0][1], 0, 0, 0);
            acc[1][0] = __builtin_amdgcn_mfma_f32_16x16x32_bf16(a1, b0, acc[1][0], 0, 0, 0);
            acc[1][1] = __builtin_amdgcn_mfma_f32_16x16x32_bf16(a1, b1, acc[1][1], 0, 0, 0);
        }
        __syncthreads();
    }
#pragma unroll
    for (int ai = 0; ai < 2; ai++)
#pragma unroll
        for (int bi = 0; bi < 2; bi++) {
            int rbase = row0 + wr * 32 + ai * 16 + (lq << 2);
            int cc = col0 + wc * 32 + bi * 16 + l15;
#pragma unroll
            for (int r = 0; r < 4; r++) {
                int rr = rbase + r;
                if (rr < Meff) Cz[(size_t)rr * ldc + cc] = acc[ai][bi][r];
            }
        }
}

__global__ __launch_bounds__(256) void k_mfma_gemm(
        const ushort* __restrict__ A, const ushort* __restrict__ Bt, float* __restrict__ C,
        int M, int Ncol, int K, int lda, int ldc, long strideBt, long strideC,
        const int* __restrict__ rowsA, const int* __restrict__ Ms,
        const int* __restrict__ rowStarts) {
    __shared__ ushort Asm[64 * 64];
    __shared__ ushort Bsm[64 * 64];
    gemm_body(A, Bt, C, M, Ncol, K, lda, ldc, strideBt, strideC, rowsA, Ms, rowStarts,
              blockIdx.z, Asm, Bsm);
}

__global__ __launch_bounds__(256) void k_mfma_dual(
        const ushort* __restrict__ A0, const ushort* __restrict__ Bt0, float* __restrict__ C0,
        int M0, int Nc0, int lda0, int ldc0, long sBt0, long sC0,
        const int* __restrict__ rows0, const int* __restrict__ rs0, int nz0,
        const ushort* __restrict__ A1, const ushort* __restrict__ Bt1, float* __restrict__ C1,
        int M1, int Nc1, int lda1, int ldc1, long sBt1, long sC1,
        const int* __restrict__ rows1, const int* __restrict__ rs1) {
    __shared__ ushort Asm[64 * 64];
    __shared__ ushort Bsm[64 * 64];
    int z = blockIdx.z;
    if (z < nz0)
        gemm_body(A0, Bt0, C0, M0, Nc0, HD, lda0, ldc0, sBt0, sC0, rows0, nullptr, rs0,
                  z, Asm, Bsm);
    else
        gemm_body(A1, Bt1, C1, M1, Nc1, HD, lda1, ldc1, sBt1, sC1, rows1, nullptr, rs1,
                  z - nz0, Asm, Bsm);
}

// ---------------------------------------------------------------- expert LN+GELU -> bf16
__global__ __launch_bounds__(256) void k_ln_gelu(const float* __restrict__ t1,
        ushort* __restrict__ ehb, const float* __restrict__ b1, const float* __restrict__ g,
        const float* __restrict__ be, const int* __restrict__ eofpos) {
    int row = blockIdx.x;
    int e = eofpos[row];
    int tid = threadIdx.x;
    __shared__ float rA[4], rB[4];
    float v[3]; float s1 = 0.f, s2 = 0.f;
#pragma unroll
    for (int r = 0; r < 3; r++) {
        int c = r * 256 + tid;
        float x = t1[(size_t)row * HD + c] + b1[e * HD + c];
        v[r] = x; s1 += x; s2 += x * x;
    }
#pragma unroll
    for (int m = 1; m < 64; m <<= 1) { s1 += __shfl_xor(s1, m); s2 += __shfl_xor(s2, m); }
    int wave = tid >> 6, lane = tid & 63;
    if (lane == 0) { rA[wave] = s1; rB[wave] = s2; }
    __syncthreads();
    float S1 = rA[0] + rA[1] + rA[2] + rA[3];
    float S2 = rB[0] + rB[1] + rB[2] + rB[3];
    float mean = S1 * (1.f / HD);
    float var = S2 * (1.f / HD) - mean * mean;
    float rstd = rsqrtf(var + 1e-5f);
#pragma unroll
    for (int r = 0; r < 3; r++) {
        int c = r * 256 + tid;
        float zn = (v[r] - mean) * rstd * g[e * HD + c] + be[e * HD + c];
        ehb[(size_t)row * HD + c] = f2bf(gelu_f(zn));
    }
}

__global__ void k_combine_moe(const float* __restrict__ eo, const float* __restrict__ b2,
        const int* __restrict__ topi, const float* __restrict__ topw,
        const int* __restrict__ posArr, float* __restrict__ h, ushort* __restrict__ hb) {
    int n = blockIdx.x;
    int tid = threadIdx.x;
    int e0 = topi[n * 2], e1 = topi[n * 2 + 1];
    float w0 = topw[n * 2], w1 = topw[n * 2 + 1];
    int p0 = posArr[n * 2], p1 = posArr[n * 2 + 1];
    for (int j = tid; j < HD; j += 256) {
        float v0 = eo[(size_t)p0 * HD + j] + b2[e0 * HD + j];
        float v1 = eo[(size_t)p1 * HD + j] + b2[e1 * HD + j];
        float hv = w0 * v0 + w1 * v1;
        h[(size_t)n * HD + j] = hv;
        hb[(size_t)n * HD + j] = f2bf(hv);
    }
}

// ---------------------------------------------------------------- GAT aggregate (el/er from fbuf ext cols)
__global__ __launch_bounds__(256) void k_gat_agg(const float* __restrict__ f,
        const int* __restrict__ src, const int* __restrict__ esorted,
        const int* __restrict__ nstart, const float* __restrict__ gb,
        float* __restrict__ hout, ushort* __restrict__ hb, float* __restrict__ outp) {
    int n = blockIdx.x;
    int s0 = nstart[n], cnt = nstart[n + 1] - s0;
    int tid = threadIdx.x;
    __shared__ float red[4][NHEADS];
    __shared__ float emax_s[NHEADS], den_s[NHEADS];
    __shared__ float alpha_s[256][NHEADS];
    __shared__ int sn_s[256];
    float4 ernv = *reinterpret_cast<const float4*>(f + (size_t)n * GATB + 3076);
    float ern[NHEADS] = { ernv.x, ernv.y, ernv.z, ernv.w };
    int wave = tid >> 6, lane = tid & 63;

    float mx[NHEADS] = { -1e30f, -1e30f, -1e30f, -1e30f };
    for (int t = tid; t < cnt; t += 256) {
        int e = esorted[s0 + t]; int sn = src[e];
        float4 elv = *reinterpret_cast<const float4*>(f + (size_t)sn * GATB + 3072);
        float el4[NHEADS] = { elv.x, elv.y, elv.z, elv.w };
#pragma unroll
        for (int hd = 0; hd < NHEADS; hd++) {
            float v = el4[hd] + ern[hd];
            v = (v >= 0.f) ? v : 0.2f * v;
            mx[hd] = fmaxf(mx[hd], v);
        }
    }
#pragma unroll
    for (int hd = 0; hd < NHEADS; hd++) {
#pragma unroll
        for (int m = 1; m < 64; m <<= 1) mx[hd] = fmaxf(mx[hd], __shfl_xor(mx[hd], m));
    }
    if (lane == 0) { for (int hd = 0; hd < NHEADS; hd++) red[wave][hd] = mx[hd]; }
    __syncthreads();
    if (tid == 0) {
#pragma unroll
        for (int hd = 0; hd < NHEADS; hd++)
            emax_s[hd] = fmaxf(fmaxf(red[0][hd], red[1][hd]), fmaxf(red[2][hd], red[3][hd]));
    }
    __syncthreads();
    float sm[NHEADS] = { 0.f, 0.f, 0.f, 0.f };
    for (int t = tid; t < cnt; t += 256) {
        int e = esorted[s0 + t]; int sn = src[e];
        float4 elv = *reinterpret_cast<const float4*>(f + (size_t)sn * GATB + 3072);
        float el4[NHEADS] = { elv.x, elv.y, elv.z, elv.w };
#pragma unroll
        for (int hd = 0; hd < NHEADS; hd++) {
            float v = el4[hd] + ern[hd];
            v = (v >= 0.f) ? v : 0.2f * v;
            sm[hd] += expf(v - emax_s[hd]);
        }
    }
#pragma unroll
    for (int hd = 0; hd < NHEADS; hd++) {
#pragma unroll
        for (int m = 1; m < 64; m <<= 1) sm[hd] += __shfl_xor(sm[hd], m);
    }
    __syncthreads();
    if (lane == 0) { for (int hd = 0; hd < NHEADS; hd++) red[wave][hd] = sm[hd]; }
    __syncthreads();
    if (tid == 0) {
#pragma unroll
        for (int hd = 0; hd < NHEADS; hd++)
            den_s[hd] = red[0][hd] + red[1][hd] + red[2][hd] + red[3][hd];
    }
    __syncthreads();
    float acc[NHEADS][3] = {};
    for (int c0 = 0; c0 < cnt; c0 += 256) {
        int t = c0 + tid;
        if (t < cnt) {
            int e = esorted[s0 + t]; int sn = src[e];
            sn_s[tid] = sn;
            float4 elv = *reinterpret_cast<const float4*>(f + (size_t)sn * GATB + 3072);
            float el4[NHEADS] = { elv.x, elv.y, elv.z, elv.w };
#pragma unroll
            for (int hd = 0; hd < NHEADS; hd++) {
                float v = el4[hd] + ern[hd];
                v = (v >= 0.f) ? v : 0.2f * v;
                alpha_s[tid][hd] = expf(v - emax_s[hd]) / fmaxf(den_s[hd], 1e-9f);
            }
        }
        __syncthreads();
        int cm = cnt - c0; if (cm > 256) cm = 256;
        for (int i = 0; i < cm; i++) {
            int sn = sn_s[i];
            const float* fr = f + (size_t)sn * GATB;
#pragma unroll
            for (int hd = 0; hd < NHEADS; hd++) {
                float a = alpha_s[i][hd];
#pragma unroll
                for (int r = 0; r < 3; r++) acc[hd][r] += a * fr[hd * HD + r * 256 + tid];
            }
        }
        __syncthreads();
    }
#pragma unroll
    for (int r = 0; r < 3; r++) {
        int j = r * 256 + tid;
        float s = 0.f;
#pragma unroll
        for (int hd = 0; hd < NHEADS; hd++) s += acc[hd][r] + gb[hd * HD + j];
        float hv = 0.25f * s;
        hout[(size_t)n * HD + j] = hv;
        hb[(size_t)n * HD + j] = f2bf(hv);
        if (outp) outp[1 + (size_t)n * HD + j] = hv;
    }
}

// ---------------------------------------------------------------- fused: SPD prep + decoder LN
__global__ __launch_bounds__(256) void k_lndec_prep(float* __restrict__ pab,
        const float* __restrict__ b1, ushort* __restrict__ pp_bf,
        float* __restrict__ Svec, float* __restrict__ Qvec,
        const float* __restrict__ t1, ushort* __restrict__ zzb,
        const float* __restrict__ db1, const float* __restrict__ dg,
        const float* __restrict__ dbe) {
    int tid = threadIdx.x;
    int wave = tid >> 6, lane = tid & 63;
    __shared__ float rA[4], rB[4];
    if (blockIdx.x >= 2 * NN) {
        int row = blockIdx.x - 2 * NN;      // 0..75
        int d = row / NMASK;
        float v[3]; float s1 = 0.f, s2 = 0.f;
#pragma unroll
        for (int r = 0; r < 3; r++) {
            int c = r * 256 + tid;
            float x = t1[(size_t)row * HD + c] + db1[d * HD + c];
            v[r] = x; s1 += x; s2 += x * x;
        }
#pragma unroll
        for (int mm = 1; mm < 64; mm <<= 1) { s1 += __shfl_xor(s1, mm); s2 += __shfl_xor(s2, mm); }
        if (lane == 0) { rA[wave] = s1; rB[wave] = s2; }
        __syncthreads();
        float S1 = rA[0] + rA[1] + rA[2] + rA[3];
        float S2 = rB[0] + rB[1] + rB[2] + rB[3];
        float mean = S1 * (1.f / HD);
        float var = S2 * (1.f / HD) - mean * mean;
        float rstd = rsqrtf(var + 1e-5f);
#pragma unroll
        for (int r = 0; r < 3; r++) {
            int c = r * 256 + tid;
            float zn = (v[r] - mean) * rstd * dg[d * HD + c] + dbe[d * HD + c];
            zzb[(size_t)row * HD + c] = f2bf(gelu_f(zn));
        }
        return;
    }
    int r = blockIdx.x;
    bool isA = r < NN;
    float* row = pab + (size_t)r * HD;
    float vv[3]; float s1 = 0.f, s2 = 0.f;
#pragma unroll
    for (int rr = 0; rr < 3; rr++) {
        int j = rr * 256 + tid;
        float v = row[j];
        if (isA) v += b1[j];
        vv[rr] = v; s1 += v; s2 += v * v;
    }
#pragma unroll
    for (int m = 1; m < 64; m <<= 1) { s1 += __shfl_xor(s1, m); s2 += __shfl_xor(s2, m); }
    if (lane == 0) { rA[wave] = s1; rB[wave] = s2; }
#pragma unroll
    for (int rr = 0; rr < 3; rr++) {
        int j = rr * 256 + tid;
        if (isA) row[j] = vv[rr];
        pp_bf[(size_t)r * HD + j] = f2bf(vv[rr]);
    }
    __syncthreads();
    if (tid == 0) {
        Svec[r] = rA[0] + rA[1] + rA[2] + rA[3];
        Qvec[r] = rB[0] + rB[1] + rB[2] + rB[3];
    }
}

// ---------------------------------------------------------------- SPD loss (packed f32x2) + cos fused
#define GC1 2.3022085f
#define GC2 0.10294429f
__global__ __launch_bounds__(256) void k_spd2(const float* __restrict__ pab,
        const float* __restrict__ Svec, const float* __restrict__ Qvec,
        const float* __restrict__ cross, const float* __restrict__ g,
        const float* __restrict__ be, const float* __restrict__ w2,
        const float* __restrict__ b2, const float* __restrict__ spd,
        float* __restrict__ partials,
        const float* __restrict__ rec, const float* __restrict__ db2,
        const int* __restrict__ mask_idx, const float* __restrict__ ft,
        const float* __restrict__ fi, float* __restrict__ rec_part) {
    int wv = threadIdx.x >> 6, lane = threadIdx.x & 63;
    if (blockIdx.y == 8) {
        int b = blockIdx.x;
        if (b >= 2 * NMASK) return;
        int d = b / NMASK, m = b % NMASK;
        int node = mask_idx[m];
        int tid = threadIdx.x;
        __shared__ float rA[4], rB[4], rC[4];
        const float* rrow = rec + (size_t)b * HD;
        const float* orig = (d == 0 ? ft : fi) + (size_t)node * HD;
        float pro = 0.f, prr = 0.f, poo = 0.f;
#pragma unroll
        for (int r = 0; r < 3; r++) {
            int c = r * 256 + tid;
            float rv = rrow[c] + db2[d * HD + c];
            float o = orig[c];
            pro += rv * o; prr += rv * rv; poo += o * o;
        }
#pragma unroll
        for (int mm = 1; mm < 64; mm <<= 1) {
            pro += __shfl_xor(pro, mm); prr += __shfl_xor(prr, mm); poo += __shfl_xor(poo, mm);
        }
        if (lane == 0) { rA[wv] = pro; rB[wv] = prr; rC[wv] = poo; }
        __syncthreads();
        if (tid == 0) {
            float P = rA[0] + rA[1] + rA[2] + rA[3];
            float R = rB[0] + rB[1] + rB[2] + rB[3];
            float O = rC[0] + rC[1] + rC[2] + rC[3];
            float denom = fmaxf(sqrtf(R) * sqrtf(O), 1e-8f);
            float cosv = P / denom;
            float t = 1.f - cosv;
            rec_part[b] = (t * t) * (1.f / (float)NMASK);
        }
        return;
    }
    int i = blockIdx.x;
    int y = blockIdx.y * 4 + wv;     // 0..31
    const f32x2* paP = reinterpret_cast<const f32x2*>(pab + (size_t)i * HD) + lane;
    const f32x2* gP  = reinterpret_cast<const f32x2*>(g) + lane;
    const f32x2* beP = reinterpret_cast<const f32x2*>(be) + lane;
    const f32x2* wP  = reinterpret_cast<const f32x2*>(w2) + lane;
    f32x2 pa2[6], g2[6], be2[6], w22[6];
#pragma unroll
    for (int s = 0; s < 6; s++) {
        pa2[s] = paP[s * 64];
        g2[s]  = gP[s * 64];
        be2[s] = beP[s * 64];
        w22[s] = wP[s * 64];
    }
#pragma unroll
    for (int s = 0; s < 6; s++) {
        asm volatile("" : "+v"(pa2[s]), "+v"(g2[s]), "+v"(be2[s]), "+v"(w22[s]));
    }
    const f32x2 C1v = (f32x2){GC1, GC1};
    const f32x2 C2v = (f32x2){GC2, GC2};
    const f32x2 one2 = (f32x2){1.f, 1.f};
    float Sa = Svec[i], Qa = Qvec[i];
    float b2v = b2[0];
    float bacc = 0.f;
#pragma unroll
    for (int t = 0; t < 6; t++) {
        int ja = y + (2 * t) * 32;
        int jb = y + (2 * t + 1) * 32;
        const f32x2* pA = reinterpret_cast<const f32x2*>(pab + (size_t)(NN + ja) * HD) + lane;
        const f32x2* pB = reinterpret_cast<const f32x2*>(pab + (size_t)(NN + jb) * HD) + lane;
        float meanA = (Sa + Svec[NN + ja]) * (1.f / HD);
        float exA = (Qa + Qvec[NN + ja] + 2.f * cross[(size_t)i * NN + ja]) * (1.f / HD);
        float rsA = rsqrtf(exA - meanA * meanA + 1e-5f);
        float nmA = -meanA * rsA;
        float meanB = (Sa + Svec[NN + jb]) * (1.f / HD);
        float exB = (Qa + Qvec[NN + jb] + 2.f * cross[(size_t)i * NN + jb]) * (1.f / HD);
        float rsB = rsqrtf(exB - meanB * meanB + 1e-5f);
        float nmB = -meanB * rsB;
        f32x2 rsA2 = (f32x2){rsA, rsA}, nmA2 = (f32x2){nmA, nmA};
        f32x2 rsB2 = (f32x2){rsB, rsB}, nmB2 = (f32x2){nmB, nmB};
        f32x2 dA = (f32x2){0.f, 0.f}, dB = (f32x2){0.f, 0.f};
#pragma unroll
        for (int s = 0; s < 6; s++) {
            f32x2 zA = pa2[s] + pA[s * 64];
            f32x2 zB = pa2[s] + pB[s * 64];
            f32x2 znA = (zA * rsA2 + nmA2) * g2[s] + be2[s];
            f32x2 znB = (zB * rsB2 + nmB2) * g2[s] + be2[s];
            f32x2 uaA = znA * (znA * znA * C2v + C1v);
            f32x2 uaB = znB * (znB * znB * C2v + C1v);
            f32x2 eA, eB;
            eA.x = __builtin_amdgcn_exp2f(-uaA.x);
            eA.y = __builtin_amdgcn_exp2f(-uaA.y);
            eB.x = __builtin_amdgcn_exp2f(-uaB.x);
            eB.y = __builtin_amdgcn_exp2f(-uaB.y);
            f32x2 qA = eA + one2;
            f32x2 qB = eB + one2;
            f32x2 rrA, rrB;
            rrA.x = __builtin_amdgcn_rcpf(qA.x);
            rrA.y = __builtin_amdgcn_rcpf(qA.y);
            rrB.x = __builtin_amdgcn_rcpf(qB.x);
            rrB.y = __builtin_amdgcn_rcpf(qB.y);
            f32x2 nwA = znA * w22[s];
            f32x2 nwB = znB * w22[s];
            dA = nwA * rrA + dA;
            dB = nwB * rrB + dB;
        }
        float dotA = dA.x + dA.y;
        float dotB = dB.x + dB.y;
#pragma unroll
        for (int m = 1; m < 64; m <<= 1) {
            dotA += __shfl_xor(dotA, m);
            dotB += __shfl_xor(dotB, m);
        }
        if (lane == 0) {
            float da = (dotA + b2v) - spd[(size_t)i * NN + ja];
            float db = (dotB + b2v) - spd[(size_t)i * NN + jb];
            bacc += da * da + db * db;
        }
    }
    if (lane == 0) partials[i * 32 + y] = bacc;
}

// ---------------------------------------------------------------- final loss reduce (single block)
__global__ __launch_bounds__(256) void k_out(const float* __restrict__ rec_part,
        const float* __restrict__ spd_part, float* __restrict__ out) {
    __shared__ float rA[4], rB[4];
    int tid = threadIdx.x;
    float sp = 0.f, rc = 0.f;
    for (int t = tid; t < 32 * NN; t += 256) sp += spd_part[t];
    for (int t = tid; t < 2 * NMASK; t += 256) rc += rec_part[t];
#pragma unroll
    for (int m = 1; m < 64; m <<= 1) { sp += __shfl_xor(sp, m); rc += __shfl_xor(rc, m); }
    int wave = tid >> 6, lane = tid & 63;
    if (lane == 0) { rA[wave] = sp; rB[wave] = rc; }
    __syncthreads();
    if (tid == 0) {
        float SP = rA[0] + rA[1] + rA[2] + rA[3];
        float RC = rB[0] + rB[1] + rB[2] + rB[3];
        out[0] = RC + 0.5f * (SP * (1.f / ((float)NN * (float)NN)));
    }
}

// ================================================================ host
extern "C" void kernel_launch(void* const* d_in, const int* in_sizes, int n_in,
                              void* d_out, int out_size, void* d_ws, size_t ws_size,
                              hipStream_t stream) {
    const float* feat_text = (const float*)d_in[0];
    const float* feat_image = (const float*)d_in[1];
    const float* spd_matrix = (const float*)d_in[2];
    const int*   src       = (const int*)d_in[3];
    const int*   dst       = (const int*)d_in[4];
    const int*   mask_idx  = (const int*)d_in[5];
    const float* mask_token = (const float*)d_in[6];
    const float* gate_W = (const float*)d_in[7];
    const float* gate_b = (const float*)d_in[8];
    const float* exp_W1 = (const float*)d_in[9];
    const float* exp_b1 = (const float*)d_in[10];
    const float* exp_g1 = (const float*)d_in[11];
    const float* exp_be1 = (const float*)d_in[12];
    const float* exp_W2 = (const float*)d_in[13];
    const float* exp_b2 = (const float*)d_in[14];
    const float* gat_W  = (const float*)d_in[15];
    const float* gat_al = (const float*)d_in[16];
    const float* gat_ar = (const float*)d_in[17];
    const float* gat_b  = (const float*)d_in[18];
    const float* dec_W1 = (const float*)d_in[19];
    const float* dec_b1 = (const float*)d_in[20];
    const float* dec_g  = (const float*)d_in[21];
    const float* dec_be = (const float*)d_in[22];
    const float* dec_W2 = (const float*)d_in[23];
    const float* dec_b2 = (const float*)d_in[24];
    const float* spd_W1 = (const float*)d_in[25];
    const float* spd_b1 = (const float*)d_in[26];
    const float* spd_g  = (const float*)d_in[27];
    const float* spd_be = (const float*)d_in[28];
    const float* spd_W2 = (const float*)d_in[29];
    const float* spd_b2 = (const float*)d_in[30];
    (void)in_sizes; (void)n_in; (void)ws_size; (void)out_size;

    float* ws = (float*)d_ws;
    size_t off = 0;
    auto alloc = [&](size_t nfl) { float* p = ws + off; off += (nfl + 3) & ~(size_t)3; return p; };
    float* hA   = alloc((size_t)NN * HD);
    float* hB   = alloc((size_t)NN * HD);
    float* t1   = alloc((size_t)NN * TOPK * HD);
    float* eo   = alloc((size_t)NN * TOPK * HD);
    float* fbuf = alloc((size_t)NN * GATB);
    float* pab  = alloc((size_t)2 * NN * HD);
    float* cross = alloc((size_t)NN * NN);
    float* Svec = alloc(2 * NN);
    float* Qvec = alloc(2 * NN);
    float* topw = alloc(NN * TOPK);
    float* rec_part = alloc(2 * NMASK + 4);
    float* spd_part = alloc(32 * NN);
    int* topi    = (int*)alloc(NN * TOPK);
    int* ecnt    = (int*)alloc(16);
    int* estart  = (int*)alloc(16);
    int* posArr  = (int*)alloc(NN * TOPK);
    int* eofpos  = (int*)alloc(NN * TOPK);
    int* rowlist = (int*)alloc(NN * TOPK);
    int* dec_rs  = (int*)alloc(4);
    int* nstart  = (int*)alloc(NN + 4);
    int* esorted = (int*)alloc(EE);
    int* counts    = (int*)alloc((size_t)NCHUNK * NN);
    int* chunkbase = (int*)alloc((size_t)NCHUNK * NN);
    ushort* xm_bf  = (ushort*)alloc((size_t)NN * HD / 2);
    ushort* eh_bf  = (ushort*)alloc((size_t)NN * TOPK * HD / 2);
    ushort* hA_bf  = (ushort*)alloc((size_t)NN * HD / 2);
    ushort* hB_bf  = (ushort*)alloc((size_t)NN * HD / 2);
    ushort* pp_bf  = (ushort*)alloc((size_t)2 * NN * HD / 2);
    ushort* expW1t = (ushort*)alloc((size_t)NEXPERT * HD * HD / 2);
    ushort* expW2t = (ushort*)alloc((size_t)NEXPERT * HD * HD / 2);
    ushort* gatWt  = (ushort*)alloc((size_t)NLAYER * GATB * HD / 2);
    ushort* spdW1t = (ushort*)alloc((size_t)2 * HD * HD / 2);
    ushort* decW1t = (ushort*)alloc((size_t)2 * HD * HD / 2);
    ushort* decW2t = (ushort*)alloc((size_t)2 * HD * HD / 2);

    // weight transposes + el/er projection rows (one dispatch)
    k_transpose_all<<<dim3(9792 + 36), dim3(256), 0, stream>>>(
        exp_W1, exp_W2, gat_W, spd_W1, dec_W1, dec_W2,
        expW1t, expW2t, gatWt, spdW1t, decW1t, decW2t, gat_al, gat_ar);

    // xm+gate (+edge histogram)
    k_xm_gate_hist<<<dim3(NN + NCHUNK), dim3(256), 0, stream>>>(
        feat_text, feat_image, mask_idx, mask_token, xm_bf, gate_W, gate_b, topi, topw,
        dst, counts);

    // edge scan + MoE meta fused
    k_scan_meta<<<dim3(2), dim3(NN), 0, stream>>>(
        counts, chunkbase, nstart, topi, ecnt, estart, posArr, eofpos, rowlist, dec_rs);
    k_rank2<<<dim3(NCHUNK), dim3(256), 0, stream>>>(dst, chunkbase, nstart, esorted);

    // experts
    k_mfma_gemm<<<dim3(HD / 64, 12, NEXPERT), dim3(256), 0, stream>>>(
        xm_bf, expW1t, t1, 0, HD, HD, HD, HD, (long)HD * HD, 0, rowlist, ecnt, estart);
    k_ln_gelu<<<dim3(NN * TOPK), dim3(256), 0, stream>>>(t1, eh_bf, exp_b1, exp_g1, exp_be1, eofpos);
    k_mfma_gemm<<<dim3(HD / 64, 12, NEXPERT), dim3(256), 0, stream>>>(
        eh_bf, expW2t, eo, 0, HD, HD, HD, HD, (long)HD * HD, 0, nullptr, ecnt, estart);
    k_combine_moe<<<dim3(NN), dim3(256), 0, stream>>>(eo, exp_b2, topi, topw, posArr, hA, hA_bf);

    // GAT layers (el/er computed inside the GEMM via appended B rows)
    float* hcur = hA; float* hnxt = hB;
    ushort* hcur_bf = hA_bf; ushort* hnxt_bf = hB_bf;
    for (int l = 0; l < NLAYER; l++) {
        k_mfma_gemm<<<dim3(GATB / 64, NN / 64, 1), dim3(256), 0, stream>>>(
            hcur_bf, gatWt + (size_t)l * GATB * HD, fbuf,
            NN, GATB, HD, HD, GATB, 0, 0, nullptr, nullptr, nullptr);
        k_gat_agg<<<dim3(NN), dim3(256), 0, stream>>>(
            fbuf, src, esorted, nstart, gat_b + (size_t)l * NHEADS * HD, hnxt, hnxt_bf,
            (l == NLAYER - 1) ? (float*)d_out : nullptr);
        float* t = hcur; hcur = hnxt; hnxt = t;
        ushort* tb = hcur_bf; hcur_bf = hnxt_bf; hnxt_bf = tb;
    }
    ushort* hfin_bf = hcur_bf;

    // dual GEMM 1: SPD projections (z=0,1) + decoder W1 (z=2,3 with row gather)
    k_mfma_dual<<<dim3(HD / 64, NN / 64, 4), dim3(256), 0, stream>>>(
        hfin_bf, spdW1t, pab, NN, HD, HD, HD, (long)HD * HD, (long)NN * HD,
        nullptr, nullptr, 2,
        hfin_bf, decW1t, t1, NMASK, HD, HD, HD, (long)HD * HD, (long)NMASK * HD,
        mask_idx, nullptr);

    // fused: SPD prep (fold b1, stats, bf16) + decoder LN+GELU
    k_lndec_prep<<<dim3(2 * NN + 2 * NMASK), dim3(256), 0, stream>>>(
        pab, spd_b1, pp_bf, Svec, Qvec, t1, eh_bf, dec_b1, dec_g, dec_be);

    // dual GEMM 2: decoder W2 (z=0,1) + SPD cross (z=2)
    k_mfma_dual<<<dim3(HD / 64, NN / 64, 3), dim3(256), 0, stream>>>(
        eh_bf, decW2t, eo, NMASK, HD, HD, HD, (long)HD * HD, 0,
        nullptr, dec_rs, 2,
        pp_bf, pp_bf + (size_t)NN * HD, cross, NN, NN, HD, NN, 0, 0,
        nullptr, nullptr);

    // SPD loss (packed) + cosine recon-loss blocks (y==8)
    k_spd2<<<dim3(NN, 9), dim3(256), 0, stream>>>(
        pab, Svec, Qvec, cross, spd_g, spd_be, spd_W2, spd_b2, spd_matrix, spd_part,
        eo, dec_b2, mask_idx, feat_text, feat_image, rec_part);

    // final loss reduce
    k_out<<<dim3(1), dim3(256), 0, stream>>>(rec_part, spd_part, (float*)d_out);
}

// Round 14
// 310.213 us; speedup vs baseline: 1.0122x; 1.0122x over previous
//
#include <hip/hip_runtime.h>
#include <hip/hip_bf16.h>
#include <math.h>

#define NN 384
#define HD 768
#define EE 12288
#define NCHUNK (EE / 256)
#define NEXPERT 8
#define TOPK 2
#define NLAYER 3
#define NHEADS 4
#define NMASK 38
#define GATB 3136   // GAT B rows: 3072 weight cols + 8 el/er rows + 56 pad

typedef __attribute__((ext_vector_type(8))) short short8v;
typedef __attribute__((ext_vector_type(4))) float f32x4;
typedef __attribute__((ext_vector_type(2))) float f32x2;
typedef __attribute__((ext_vector_type(4))) int int4v;

__device__ __forceinline__ float gelu_f(float x) {
    return x * 0.5f * (1.f + erff(x * 0.70710678118654752440f));
}

__device__ __forceinline__ ushort f2bf(float x) {
    unsigned u = __float_as_uint(x);
    u += 0x7fffu + ((u >> 16) & 1u);
    return (ushort)(u >> 16);
}

// ---------------------------------------------------------------- fused xm+gate (+edge hist)
__global__ __launch_bounds__(256) void k_xm_gate_hist(const float* __restrict__ a,
        const float* __restrict__ b, const int* __restrict__ mask_idx,
        const float* __restrict__ mt, ushort* __restrict__ xm_bf,
        const float* __restrict__ gW, const float* __restrict__ gb,
        int* __restrict__ topi, float* __restrict__ topw,
        const int* __restrict__ dst, int* __restrict__ counts) {
    if (blockIdx.x >= NN) {
        __shared__ int h[NN];
        int c = blockIdx.x - NN;
        for (int i = threadIdx.x; i < NN; i += 256) h[i] = 0;
        __syncthreads();
        atomicAdd(&h[dst[c * 256 + threadIdx.x]], 1);
        __syncthreads();
        for (int i = threadIdx.x; i < NN; i += 256) counts[c * NN + i] = h[i];
        return;
    }
    int n = blockIdx.x, tid = threadIdx.x;
    __shared__ float xs[HD];
    __shared__ int ism;
    __shared__ float logits[NEXPERT];
    if (tid == 0) ism = 0;
    __syncthreads();
    if (tid < NMASK && mask_idx[tid] == n) ism = 1;
    __syncthreads();
#pragma unroll
    for (int r = 0; r < 3; r++) {
        int j = r * 256 + tid;
        float v = ism ? mt[j] : 0.5f * (a[(size_t)n * HD + j] + b[(size_t)n * HD + j]);
        xs[j] = v;
        xm_bf[(size_t)n * HD + j] = f2bf(v);
    }
    __syncthreads();
    int grp = tid >> 5;
    int l32 = tid & 31;
    float p = 0.f;
    for (int dd = l32; dd < HD; dd += 32) p += xs[dd] * gW[dd * NEXPERT + grp];
#pragma unroll
    for (int m = 1; m < 32; m <<= 1) p += __shfl_xor(p, m, 32);
    if (l32 == 0) logits[grp] = p + gb[grp];
    __syncthreads();
    if (tid == 0) {
        float mx = logits[0];
#pragma unroll
        for (int e = 1; e < NEXPERT; e++) mx = fmaxf(mx, logits[e]);
        float sm[NEXPERT]; float s = 0.f;
#pragma unroll
        for (int e = 0; e < NEXPERT; e++) { sm[e] = expf(logits[e] - mx); s += sm[e]; }
#pragma unroll
        for (int e = 0; e < NEXPERT; e++) sm[e] /= s;
        int i0 = 0; float b0 = sm[0];
#pragma unroll
        for (int e = 1; e < NEXPERT; e++) if (sm[e] > b0) { b0 = sm[e]; i0 = e; }
        int i1 = -1; float b1v = -1.f;
#pragma unroll
        for (int e = 0; e < NEXPERT; e++) if (e != i0 && sm[e] > b1v) { b1v = sm[e]; i1 = e; }
        float ssum = b0 + b1v;
        topi[n * 2] = i0; topi[n * 2 + 1] = i1;
        topw[n * 2] = b0 / ssum; topw[n * 2 + 1] = b1v / ssum;
    }
}

// ---------------------------------------------------------------- all weight transposes (R12 body, small LDS)
__global__ __launch_bounds__(256) void k_transpose_all(
        const float* __restrict__ w1, const float* __restrict__ w2,
        const float* __restrict__ gw, const float* __restrict__ sw,
        const float* __restrict__ dw1, const float* __restrict__ dw2,
        ushort* __restrict__ o1, ushort* __restrict__ o2, ushort* __restrict__ og,
        ushort* __restrict__ os, ushort* __restrict__ od1, ushort* __restrict__ od2) {
    int b = blockIdx.x;
    const float* src; ushort* dst; int N, loc, tilesX; size_t outStrideZ;
    if (b < 2304)      { src = w1;  dst = o1;  N = HD;     loc = b;        tilesX = 24; outStrideZ = (size_t)HD * HD; }
    else if (b < 4608) { src = w2;  dst = o2;  N = HD;     loc = b - 2304; tilesX = 24; outStrideZ = (size_t)HD * HD; }
    else if (b < 8064) { src = gw;  dst = og;  N = 4 * HD; loc = b - 4608; tilesX = 96; outStrideZ = (size_t)GATB * HD; }
    else if (b < 8640) { src = sw;  dst = os;  N = HD;     loc = b - 8064; tilesX = 24; outStrideZ = (size_t)HD * HD; }
    else if (b < 9216) { src = dw1; dst = od1; N = HD;     loc = b - 8640; tilesX = 24; outStrideZ = (size_t)HD * HD; }
    else               { src = dw2; dst = od2; N = HD;     loc = b - 9216; tilesX = 24; outStrideZ = (size_t)HD * HD; }
    const int K = HD;
    int tilesPerZ = tilesX * 12;
    int z = loc / tilesPerZ;
    int rem = loc - z * tilesPerZ;
    int ty = rem / tilesX, tx = rem - ty * tilesX;
    const float* inz = src + (size_t)z * K * N;
    ushort* outz = dst + (size_t)z * outStrideZ;
    int n0 = tx * 32, k0 = ty * 64;

    __shared__ float t[64][33];
    int r = threadIdx.x >> 2, c8 = (threadIdx.x & 3) * 8;
    const float* ip = inz + (size_t)(k0 + r) * N + n0 + c8;
    float4 va = *reinterpret_cast<const float4*>(ip);
    float4 vb = *reinterpret_cast<const float4*>(ip + 4);
    t[r][c8 + 0] = va.x; t[r][c8 + 1] = va.y; t[r][c8 + 2] = va.z; t[r][c8 + 3] = va.w;
    t[r][c8 + 4] = vb.x; t[r][c8 + 5] = vb.y; t[r][c8 + 6] = vb.z; t[r][c8 + 7] = vb.w;
    __syncthreads();
    int nn = threadIdx.x >> 3;
    int kk = (threadIdx.x & 7) * 8;
    uint4 o;
    uint pk[4];
#pragma unroll
    for (int q = 0; q < 4; q++) {
        ushort lo = f2bf(t[kk + 2 * q][nn]);
        ushort hi = f2bf(t[kk + 2 * q + 1][nn]);
        pk[q] = (uint)lo | ((uint)hi << 16);
    }
    o.x = pk[0]; o.y = pk[1]; o.z = pk[2]; o.w = pk[3];
    *reinterpret_cast<uint4*>(outz + (size_t)(n0 + nn) * K + k0 + kk) = o;
}

// ---------------------------------------------------------------- el/er projection rows (separate kernel)
// og[l][3072+ri][k] = sum_j gw_l[k][(ri&3)*768+j] * a[ri][j], a = {al rows 0-3, ar rows 4-7}
__global__ __launch_bounds__(256) void k_elproj(const float* __restrict__ gw,
        const float* __restrict__ gal, const float* __restrict__ gar,
        ushort* __restrict__ og) {
    __shared__ float aLDS[8 * HD];
    __shared__ float red[4][64][9];
    int b2 = blockIdx.x;          // 0..35
    int tid = threadIdx.x;
    int l = b2 / 12, kc = b2 % 12;
    for (int idx = tid; idx < 8 * HD; idx += 256) {
        int ri = idx / HD, j = idx - ri * HD;
        aLDS[idx] = (ri < 4) ? gal[((size_t)l * 4 + ri) * HD + j]
                             : gar[((size_t)l * 4 + (ri - 4)) * HD + j];
    }
    __syncthreads();
    int q = tid >> 6, kk = tid & 63;
    int k = kc * 64 + kk;
    const float* wrow = gw + ((size_t)l * HD + k) * (4 * HD);
    float acc[8] = {};
    for (int j = q * 192; j < q * 192 + 192; j++) {
        float w0 = wrow[0 * HD + j], w1v = wrow[1 * HD + j];
        float w2v = wrow[2 * HD + j], w3 = wrow[3 * HD + j];
        acc[0] += w0 * aLDS[0 * HD + j]; acc[4] += w0 * aLDS[4 * HD + j];
        acc[1] += w1v * aLDS[1 * HD + j]; acc[5] += w1v * aLDS[5 * HD + j];
        acc[2] += w2v * aLDS[2 * HD + j]; acc[6] += w2v * aLDS[6 * HD + j];
        acc[3] += w3 * aLDS[3 * HD + j]; acc[7] += w3 * aLDS[7 * HD + j];
    }
#pragma unroll
    for (int ri = 0; ri < 8; ri++) red[q][kk][ri] = acc[ri];
    __syncthreads();
    if (tid < 64) {
#pragma unroll
        for (int ri = 0; ri < 8; ri++) {
            float s = red[0][tid][ri] + red[1][tid][ri] + red[2][tid][ri] + red[3][tid][ri];
            og[(size_t)l * GATB * HD + (size_t)(3072 + ri) * HD + kc * 64 + tid] = f2bf(s);
        }
    }
}

// ---------------------------------------------------------------- fused scan (edges) + MoE meta
__global__ __launch_bounds__(NN) void k_scan_meta(const int* __restrict__ counts,
        int* __restrict__ chunkbase, int* __restrict__ nstart,
        const int* __restrict__ topi, int* __restrict__ ecnt, int* __restrict__ estart,
        int* __restrict__ posArr, int* __restrict__ eofpos, int* __restrict__ rowlist,
        int* __restrict__ dec_rs) {
    int tid = threadIdx.x;
    if (blockIdx.x == 0) {
        __shared__ int tot[NN];
        int n = tid;
        int s = 0;
        for (int c = 0; c < NCHUNK; c++) { chunkbase[c * NN + n] = s; s += counts[c * NN + n]; }
        tot[n] = s;
        __syncthreads();
        for (int off = 1; off < NN; off <<= 1) {
            int v = tot[n];
            int add = (n >= off) ? tot[n - off] : 0;
            __syncthreads();
            tot[n] = v + add;
            __syncthreads();
        }
        nstart[n + 1] = tot[n];
        if (n == 0) nstart[0] = 0;
        return;
    }
    __shared__ int ti[NN * TOPK];
    __shared__ int cnt[NEXPERT];
    __shared__ int est[NEXPERT + 1];
    if (tid < NEXPERT) cnt[tid] = 0;
    __syncthreads();
    for (int a = tid; a < NN * TOPK; a += NN) ti[a] = topi[a];
    __syncthreads();
    for (int a = tid; a < NN * TOPK; a += NN) atomicAdd(&cnt[ti[a]], 1);
    __syncthreads();
    if (tid == 0) {
        int s = 0;
        for (int e = 0; e < NEXPERT; e++) { est[e] = s; s += cnt[e]; }
        est[NEXPERT] = s;
        dec_rs[0] = 0; dec_rs[1] = NMASK;
    }
    __syncthreads();
    if (tid < NEXPERT) { ecnt[tid] = cnt[tid]; estart[tid] = est[tid]; }
    if (tid == 0) estart[NEXPERT] = est[NEXPERT];
    for (int a = tid; a < NN * TOPK; a += NN) {
        int e = ti[a]; int rank = 0;
        for (int a2 = 0; a2 < a; a2++) rank += (ti[a2] == e) ? 1 : 0;
        int p = est[e] + rank;
        posArr[a] = p; eofpos[p] = e; rowlist[p] = a >> 1;
    }
}

__global__ __launch_bounds__(256) void k_rank2(const int* __restrict__ dst,
        const int* __restrict__ chunkbase, const int* __restrict__ nstart,
        int* __restrict__ esorted) {
    __shared__ int ds[256];
    int c = blockIdx.x;
    int e = c * 256 + threadIdx.x;
    int d = dst[e];
    ds[threadIdx.x] = d;
    __syncthreads();
    int r = 0;
    for (int i = 0; i < threadIdx.x; i++) r += (ds[i] == d) ? 1 : 0;
    esorted[nstart[d] + chunkbase[c * NN + d] + r] = e;
}

// ---------------------------------------------------------------- bf16 MFMA GEMM (pipelined body)
__device__ __forceinline__ short8v ldfrag(const ushort* s, int r, int kb) {
    int c = kb ^ (r & 7);
    return *reinterpret_cast<const short8v*>(s + r * 64 + c * 8);
}

__device__ __forceinline__ void gemm_body(
        const ushort* __restrict__ A, const ushort* __restrict__ Bt, float* __restrict__ C,
        int M, int Ncol, int K, int lda, int ldc, long strideBt, long strideC,
        const int* __restrict__ rowsA, const int* __restrict__ Ms,
        const int* __restrict__ rowStarts, int z, ushort* Asm, ushort* Bsm) {
    int Meff = Ms ? Ms[z] : M;
    int row0 = blockIdx.y * 64;
    if (row0 >= Meff) return;
    int col0 = blockIdx.x * 64;
    if (col0 >= Ncol) return;
    int rowbase = rowStarts ? rowStarts[z] : 0;
    const ushort* Btz = Bt + (size_t)z * strideBt;
    float* Cz = C + (size_t)rowbase * ldc + (size_t)z * strideC;
    const int* rz = rowsA ? (rowsA + rowbase) : nullptr;

    int tid = threadIdx.x;
    int w = tid >> 6, lane = tid & 63;
    int wr = w >> 1, wc = w & 1;
    int l15 = lane & 15, lq = lane >> 4;

    int r0s = tid >> 3, c0s = tid & 7;
    int cs0 = c0s ^ (r0s & 7);
    int r1s = r0s + 32;
    int cs1 = c0s ^ (r1s & 7);
    int grow0 = row0 + r0s, grow1 = row0 + r1s;
    bool ok0 = grow0 < Meff, ok1 = grow1 < Meff;
    int srow0 = ok0 ? (rz ? rz[grow0] : rowbase + grow0) : (rz ? rz[0] : rowbase);
    int srow1 = ok1 ? (rz ? rz[grow1] : rowbase + grow1) : (rz ? rz[0] : rowbase);
    const ushort* aP0 = A + (size_t)srow0 * lda + c0s * 8;
    const ushort* aP1 = A + (size_t)srow1 * lda + c0s * 8;
    const ushort* bP0 = Btz + (size_t)(col0 + r0s) * K + c0s * 8;
    const ushort* bP1 = Btz + (size_t)(col0 + r1s) * K + c0s * 8;
    ushort* asm0 = &Asm[r0s * 64 + cs0 * 8];
    ushort* asm1 = &Asm[r1s * 64 + cs1 * 8];
    ushort* bsm0 = &Bsm[r0s * 64 + cs0 * 8];
    ushort* bsm1 = &Bsm[r1s * 64 + cs1 * 8];
    const int4v z4 = (int4v){0, 0, 0, 0};

    f32x4 acc[2][2];
#pragma unroll
    for (int i = 0; i < 2; i++)
#pragma unroll
        for (int j = 0; j < 2; j++) acc[i][j] = (f32x4){0.f, 0.f, 0.f, 0.f};

    int4v ta0 = *reinterpret_cast<const int4v*>(aP0);
    int4v ta1 = *reinterpret_cast<const int4v*>(aP1);
    int4v av0 = ok0 ? ta0 : z4;
    int4v av1 = ok1 ? ta1 : z4;
    int4v bv0 = *reinterpret_cast<const int4v*>(bP0);
    int4v bv1 = *reinterpret_cast<const int4v*>(bP1);

    for (int k0 = 0; k0 < K; k0 += 64) {
        *reinterpret_cast<int4v*>(asm0) = av0;
        *reinterpret_cast<int4v*>(asm1) = av1;
        *reinterpret_cast<int4v*>(bsm0) = bv0;
        *reinterpret_cast<int4v*>(bsm1) = bv1;
        __syncthreads();
        int kn = k0 + 64;
        if (kn < K) {
            int4v na0 = *reinterpret_cast<const int4v*>(aP0 + kn);
            int4v na1 = *reinterpret_cast<const int4v*>(aP1 + kn);
            av0 = ok0 ? na0 : z4;
            av1 = ok1 ? na1 : z4;
            bv0 = *reinterpret_cast<const int4v*>(bP0 + kn);
            bv1 = *reinterpret_cast<const int4v*>(bP1 + kn);
        }
#pragma unroll
        for (int ks = 0; ks < 2; ks++) {
            int kb = ks * 4 + lq;
            short8v a0 = ldfrag(Asm, wr * 32 + l15, kb);
            short8v a1 = ldfrag(Asm, wr * 32 + 16 + l15, kb);
            short8v b0 = ldfrag(Bsm, wc * 32 + l15, kb);
            short8v b1 = ldfrag(Bsm, wc * 32 + 16 + l15, kb);
            acc[0][0] = __builtin_amdgcn_mfma_f32_16x16x32_bf16(a0, b0, acc[0][0], 0, 0, 0);
            acc[0][1] = __builtin_amdgcn_mfma_f32_16x16x32_bf16(a0, b1, acc[0][1], 0, 0, 0);
            acc[1][0] = __builtin_amdgcn_mfma_f32_16x16x32_bf16(a1, b0, acc[1][0], 0, 0, 0);
            acc[1][1] = __builtin_amdgcn_mfma_f32_16x16x32_bf16(a1, b1, acc[1][1], 0, 0, 0);
        }
        __syncthreads();
    }
#pragma unroll
    for (int ai = 0; ai < 2; ai++)
#pragma unroll
        for (int bi = 0; bi < 2; bi++) {
            int rbase = row0 + wr * 32 + ai * 16 + (lq << 2);
            int cc = col0 + wc * 32 + bi * 16 + l15;
#pragma unroll
            for (int r = 0; r < 4; r++) {
                int rr = rbase + r;
                if (rr < Meff) Cz[(size_t)rr * ldc + cc] = acc[ai][bi][r];
            }
        }
}

__global__ __launch_bounds__(256) void k_mfma_gemm(
        const ushort* __restrict__ A, const ushort* __restrict__ Bt, float* __restrict__ C,
        int M, int Ncol, int K, int lda, int ldc, long strideBt, long strideC,
        const int* __restrict__ rowsA, const int* __restrict__ Ms,
        const int* __restrict__ rowStarts) {
    __shared__ ushort Asm[64 * 64];
    __shared__ ushort Bsm[64 * 64];
    gemm_body(A, Bt, C, M, Ncol, K, lda, ldc, strideBt, strideC, rowsA, Ms, rowStarts,
              blockIdx.z, Asm, Bsm);
}

__global__ __launch_bounds__(256) void k_mfma_dual(
        const ushort* __restrict__ A0, const ushort* __restrict__ Bt0, float* __restrict__ C0,
        int M0, int Nc0, int lda0, int ldc0, long sBt0, long sC0,
        const int* __restrict__ rows0, const int* __restrict__ rs0, int nz0,
        const ushort* __restrict__ A1, const ushort* __restrict__ Bt1, float* __restrict__ C1,
        int M1, int Nc1, int lda1, int ldc1, long sBt1, long sC1,
        const int* __restrict__ rows1, const int* __restrict__ rs1) {
    __shared__ ushort Asm[64 * 64];
    __shared__ ushort Bsm[64 * 64];
    int z = blockIdx.z;
    if (z < nz0)
        gemm_body(A0, Bt0, C0, M0, Nc0, HD, lda0, ldc0, sBt0, sC0, rows0, nullptr, rs0,
                  z, Asm, Bsm);
    else
        gemm_body(A1, Bt1, C1, M1, Nc1, HD, lda1, ldc1, sBt1, sC1, rows1, nullptr, rs1,
                  z - nz0, Asm, Bsm);
}

// ---------------------------------------------------------------- expert LN+GELU -> bf16
__global__ __launch_bounds__(256) void k_ln_gelu(const float* __restrict__ t1,
        ushort* __restrict__ ehb, const float* __restrict__ b1, const float* __restrict__ g,
        const float* __restrict__ be, const int* __restrict__ eofpos) {
    int row = blockIdx.x;
    int e = eofpos[row];
    int tid = threadIdx.x;
    __shared__ float rA[4], rB[4];
    float v[3]; float s1 = 0.f, s2 = 0.f;
#pragma unroll
    for (int r = 0; r < 3; r++) {
        int c = r * 256 + tid;
        float x = t1[(size_t)row * HD + c] + b1[e * HD + c];
        v[r] = x; s1 += x; s2 += x * x;
    }
#pragma unroll
    for (int m = 1; m < 64; m <<= 1) { s1 += __shfl_xor(s1, m); s2 += __shfl_xor(s2, m); }
    int wave = tid >> 6, lane = tid & 63;
    if (lane == 0) { rA[wave] = s1; rB[wave] = s2; }
    __syncthreads();
    float S1 = rA[0] + rA[1] + rA[2] + rA[3];
    float S2 = rB[0] + rB[1] + rB[2] + rB[3];
    float mean = S1 * (1.f / HD);
    float var = S2 * (1.f / HD) - mean * mean;
    float rstd = rsqrtf(var + 1e-5f);
#pragma unroll
    for (int r = 0; r < 3; r++) {
        int c = r * 256 + tid;
        float zn = (v[r] - mean) * rstd * g[e * HD + c] + be[e * HD + c];
        ehb[(size_t)row * HD + c] = f2bf(gelu_f(zn));
    }
}

__global__ void k_combine_moe(const float* __restrict__ eo, const float* __restrict__ b2,
        const int* __restrict__ topi, const float* __restrict__ topw,
        const int* __restrict__ posArr, float* __restrict__ h, ushort* __restrict__ hb) {
    int n = blockIdx.x;
    int tid = threadIdx.x;
    int e0 = topi[n * 2], e1 = topi[n * 2 + 1];
    float w0 = topw[n * 2], w1 = topw[n * 2 + 1];
    int p0 = posArr[n * 2], p1 = posArr[n * 2 + 1];
    for (int j = tid; j < HD; j += 256) {
        float v0 = eo[(size_t)p0 * HD + j] + b2[e0 * HD + j];
        float v1 = eo[(size_t)p1 * HD + j] + b2[e1 * HD + j];
        float hv = w0 * v0 + w1 * v1;
        h[(size_t)n * HD + j] = hv;
        hb[(size_t)n * HD + j] = f2bf(hv);
    }
}

// ---------------------------------------------------------------- GAT aggregate (el/er from fbuf ext cols)
__global__ __launch_bounds__(256) void k_gat_agg(const float* __restrict__ f,
        const int* __restrict__ src, const int* __restrict__ esorted,
        const int* __restrict__ nstart, const float* __restrict__ gb,
        float* __restrict__ hout, ushort* __restrict__ hb, float* __restrict__ outp) {
    int n = blockIdx.x;
    int s0 = nstart[n], cnt = nstart[n + 1] - s0;
    int tid = threadIdx.x;
    __shared__ float red[4][NHEADS];
    __shared__ float emax_s[NHEADS], den_s[NHEADS];
    __shared__ float alpha_s[256][NHEADS];
    __shared__ int sn_s[256];
    float4 ernv = *reinterpret_cast<const float4*>(f + (size_t)n * GATB + 3076);
    float ern[NHEADS] = { ernv.x, ernv.y, ernv.z, ernv.w };
    int wave = tid >> 6, lane = tid & 63;

    float mx[NHEADS] = { -1e30f, -1e30f, -1e30f, -1e30f };
    for (int t = tid; t < cnt; t += 256) {
        int e = esorted[s0 + t]; int sn = src[e];
        float4 elv = *reinterpret_cast<const float4*>(f + (size_t)sn * GATB + 3072);
        float el4[NHEADS] = { elv.x, elv.y, elv.z, elv.w };
#pragma unroll
        for (int hd = 0; hd < NHEADS; hd++) {
            float v = el4[hd] + ern[hd];
            v = (v >= 0.f) ? v : 0.2f * v;
            mx[hd] = fmaxf(mx[hd], v);
        }
    }
#pragma unroll
    for (int hd = 0; hd < NHEADS; hd++) {
#pragma unroll
        for (int m = 1; m < 64; m <<= 1) mx[hd] = fmaxf(mx[hd], __shfl_xor(mx[hd], m));
    }
    if (lane == 0) { for (int hd = 0; hd < NHEADS; hd++) red[wave][hd] = mx[hd]; }
    __syncthreads();
    if (tid == 0) {
#pragma unroll
        for (int hd = 0; hd < NHEADS; hd++)
            emax_s[hd] = fmaxf(fmaxf(red[0][hd], red[1][hd]), fmaxf(red[2][hd], red[3][hd]));
    }
    __syncthreads();
    float sm[NHEADS] = { 0.f, 0.f, 0.f, 0.f };
    for (int t = tid; t < cnt; t += 256) {
        int e = esorted[s0 + t]; int sn = src[e];
        float4 elv = *reinterpret_cast<const float4*>(f + (size_t)sn * GATB + 3072);
        float el4[NHEADS] = { elv.x, elv.y, elv.z, elv.w };
#pragma unroll
        for (int hd = 0; hd < NHEADS; hd++) {
            float v = el4[hd] + ern[hd];
            v = (v >= 0.f) ? v : 0.2f * v;
            sm[hd] += expf(v - emax_s[hd]);
        }
    }
#pragma unroll
    for (int hd = 0; hd < NHEADS; hd++) {
#pragma unroll
        for (int m = 1; m < 64; m <<= 1) sm[hd] += __shfl_xor(sm[hd], m);
    }
    __syncthreads();
    if (lane == 0) { for (int hd = 0; hd < NHEADS; hd++) red[wave][hd] = sm[hd]; }
    __syncthreads();
    if (tid == 0) {
#pragma unroll
        for (int hd = 0; hd < NHEADS; hd++)
            den_s[hd] = red[0][hd] + red[1][hd] + red[2][hd] + red[3][hd];
    }
    __syncthreads();
    float acc[NHEADS][3] = {};
    for (int c0 = 0; c0 < cnt; c0 += 256) {
        int t = c0 + tid;
        if (t < cnt) {
            int e = esorted[s0 + t]; int sn = src[e];
            sn_s[tid] = sn;
            float4 elv = *reinterpret_cast<const float4*>(f + (size_t)sn * GATB + 3072);
            float el4[NHEADS] = { elv.x, elv.y, elv.z, elv.w };
#pragma unroll
            for (int hd = 0; hd < NHEADS; hd++) {
                float v = el4[hd] + ern[hd];
                v = (v >= 0.f) ? v : 0.2f * v;
                alpha_s[tid][hd] = expf(v - emax_s[hd]) / fmaxf(den_s[hd], 1e-9f);
            }
        }
        __syncthreads();
        int cm = cnt - c0; if (cm > 256) cm = 256;
        for (int i = 0; i < cm; i++) {
            int sn = sn_s[i];
            const float* fr = f + (size_t)sn * GATB;
#pragma unroll
            for (int hd = 0; hd < NHEADS; hd++) {
                float a = alpha_s[i][hd];
#pragma unroll
                for (int r = 0; r < 3; r++) acc[hd][r] += a * fr[hd * HD + r * 256 + tid];
            }
        }
        __syncthreads();
    }
#pragma unroll
    for (int r = 0; r < 3; r++) {
        int j = r * 256 + tid;
        float s = 0.f;
#pragma unroll
        for (int hd = 0; hd < NHEADS; hd++) s += acc[hd][r] + gb[hd * HD + j];
        float hv = 0.25f * s;
        hout[(size_t)n * HD + j] = hv;
        hb[(size_t)n * HD + j] = f2bf(hv);
        if (outp) outp[1 + (size_t)n * HD + j] = hv;
    }
}

// ---------------------------------------------------------------- fused: SPD prep + decoder LN
__global__ __launch_bounds__(256) void k_lndec_prep(float* __restrict__ pab,
        const float* __restrict__ b1, ushort* __restrict__ pp_bf,
        float* __restrict__ Svec, float* __restrict__ Qvec,
        const float* __restrict__ t1, ushort* __restrict__ zzb,
        const float* __restrict__ db1, const float* __restrict__ dg,
        const float* __restrict__ dbe) {
    int tid = threadIdx.x;
    int wave = tid >> 6, lane = tid & 63;
    __shared__ float rA[4], rB[4];
    if (blockIdx.x >= 2 * NN) {
        int row = blockIdx.x - 2 * NN;      // 0..75
        int d = row / NMASK;
        float v[3]; float s1 = 0.f, s2 = 0.f;
#pragma unroll
        for (int r = 0; r < 3; r++) {
            int c = r * 256 + tid;
            float x = t1[(size_t)row * HD + c] + db1[d * HD + c];
            v[r] = x; s1 += x; s2 += x * x;
        }
#pragma unroll
        for (int mm = 1; mm < 64; mm <<= 1) { s1 += __shfl_xor(s1, mm); s2 += __shfl_xor(s2, mm); }
        if (lane == 0) { rA[wave] = s1; rB[wave] = s2; }
        __syncthreads();
        float S1 = rA[0] + rA[1] + rA[2] + rA[3];
        float S2 = rB[0] + rB[1] + rB[2] + rB[3];
        float mean = S1 * (1.f / HD);
        float var = S2 * (1.f / HD) - mean * mean;
        float rstd = rsqrtf(var + 1e-5f);
#pragma unroll
        for (int r = 0; r < 3; r++) {
            int c = r * 256 + tid;
            float zn = (v[r] - mean) * rstd * dg[d * HD + c] + dbe[d * HD + c];
            zzb[(size_t)row * HD + c] = f2bf(gelu_f(zn));
        }
        return;
    }
    int r = blockIdx.x;
    bool isA = r < NN;
    float* row = pab + (size_t)r * HD;
    float vv[3]; float s1 = 0.f, s2 = 0.f;
#pragma unroll
    for (int rr = 0; rr < 3; rr++) {
        int j = rr * 256 + tid;
        float v = row[j];
        if (isA) v += b1[j];
        vv[rr] = v; s1 += v; s2 += v * v;
    }
#pragma unroll
    for (int m = 1; m < 64; m <<= 1) { s1 += __shfl_xor(s1, m); s2 += __shfl_xor(s2, m); }
    if (lane == 0) { rA[wave] = s1; rB[wave] = s2; }
#pragma unroll
    for (int rr = 0; rr < 3; rr++) {
        int j = rr * 256 + tid;
        if (isA) row[j] = vv[rr];
        pp_bf[(size_t)r * HD + j] = f2bf(vv[rr]);
    }
    __syncthreads();
    if (tid == 0) {
        Svec[r] = rA[0] + rA[1] + rA[2] + rA[3];
        Qvec[r] = rB[0] + rB[1] + rB[2] + rB[3];
    }
}

// ---------------------------------------------------------------- SPD loss (packed f32x2) + cos fused
#define GC1 2.3022085f
#define GC2 0.10294429f
__global__ __launch_bounds__(256) void k_spd2(const float* __restrict__ pab,
        const float* __restrict__ Svec, const float* __restrict__ Qvec,
        const float* __restrict__ cross, const float* __restrict__ g,
        const float* __restrict__ be, const float* __restrict__ w2,
        const float* __restrict__ b2, const float* __restrict__ spd,
        float* __restrict__ partials,
        const float* __restrict__ rec, const float* __restrict__ db2,
        const int* __restrict__ mask_idx, const float* __restrict__ ft,
        const float* __restrict__ fi, float* __restrict__ rec_part) {
    int wv = threadIdx.x >> 6, lane = threadIdx.x & 63;
    if (blockIdx.y == 8) {
        int b = blockIdx.x;
        if (b >= 2 * NMASK) return;
        int d = b / NMASK, m = b % NMASK;
        int node = mask_idx[m];
        int tid = threadIdx.x;
        __shared__ float rA[4], rB[4], rC[4];
        const float* rrow = rec + (size_t)b * HD;
        const float* orig = (d == 0 ? ft : fi) + (size_t)node * HD;
        float pro = 0.f, prr = 0.f, poo = 0.f;
#pragma unroll
        for (int r = 0; r < 3; r++) {
            int c = r * 256 + tid;
            float rv = rrow[c] + db2[d * HD + c];
            float o = orig[c];
            pro += rv * o; prr += rv * rv; poo += o * o;
        }
#pragma unroll
        for (int mm = 1; mm < 64; mm <<= 1) {
            pro += __shfl_xor(pro, mm); prr += __shfl_xor(prr, mm); poo += __shfl_xor(poo, mm);
        }
        if (lane == 0) { rA[wv] = pro; rB[wv] = prr; rC[wv] = poo; }
        __syncthreads();
        if (tid == 0) {
            float P = rA[0] + rA[1] + rA[2] + rA[3];
            float R = rB[0] + rB[1] + rB[2] + rB[3];
            float O = rC[0] + rC[1] + rC[2] + rC[3];
            float denom = fmaxf(sqrtf(R) * sqrtf(O), 1e-8f);
            float cosv = P / denom;
            float t = 1.f - cosv;
            rec_part[b] = (t * t) * (1.f / (float)NMASK);
        }
        return;
    }
    int i = blockIdx.x;
    int y = blockIdx.y * 4 + wv;     // 0..31
    const f32x2* paP = reinterpret_cast<const f32x2*>(pab + (size_t)i * HD) + lane;
    const f32x2* gP  = reinterpret_cast<const f32x2*>(g) + lane;
    const f32x2* beP = reinterpret_cast<const f32x2*>(be) + lane;
    const f32x2* wP  = reinterpret_cast<const f32x2*>(w2) + lane;
    f32x2 pa2[6], g2[6], be2[6], w22[6];
#pragma unroll
    for (int s = 0; s < 6; s++) {
        pa2[s] = paP[s * 64];
        g2[s]  = gP[s * 64];
        be2[s] = beP[s * 64];
        w22[s] = wP[s * 64];
    }
#pragma unroll
    for (int s = 0; s < 6; s++) {
        asm volatile("" : "+v"(pa2[s]), "+v"(g2[s]), "+v"(be2[s]), "+v"(w22[s]));
    }
    const f32x2 C1v = (f32x2){GC1, GC1};
    const f32x2 C2v = (f32x2){GC2, GC2};
    const f32x2 one2 = (f32x2){1.f, 1.f};
    float Sa = Svec[i], Qa = Qvec[i];
    float b2v = b2[0];
    float bacc = 0.f;
#pragma unroll
    for (int t = 0; t < 6; t++) {
        int ja = y + (2 * t) * 32;
        int jb = y + (2 * t + 1) * 32;
        const f32x2* pA = reinterpret_cast<const f32x2*>(pab + (size_t)(NN + ja) * HD) + lane;
        const f32x2* pB = reinterpret_cast<const f32x2*>(pab + (size_t)(NN + jb) * HD) + lane;
        float meanA = (Sa + Svec[NN + ja]) * (1.f / HD);
        float exA = (Qa + Qvec[NN + ja] + 2.f * cross[(size_t)i * NN + ja]) * (1.f / HD);
        float rsA = rsqrtf(exA - meanA * meanA + 1e-5f);
        float nmA = -meanA * rsA;
        float meanB = (Sa + Svec[NN + jb]) * (1.f / HD);
        float exB = (Qa + Qvec[NN + jb] + 2.f * cross[(size_t)i * NN + jb]) * (1.f / HD);
        float rsB = rsqrtf(exB - meanB * meanB + 1e-5f);
        float nmB = -meanB * rsB;
        f32x2 rsA2 = (f32x2){rsA, rsA}, nmA2 = (f32x2){nmA, nmA};
        f32x2 rsB2 = (f32x2){rsB, rsB}, nmB2 = (f32x2){nmB, nmB};
        f32x2 dA = (f32x2){0.f, 0.f}, dB = (f32x2){0.f, 0.f};
#pragma unroll
        for (int s = 0; s < 6; s++) {
            f32x2 zA = pa2[s] + pA[s * 64];
            f32x2 zB = pa2[s] + pB[s * 64];
            f32x2 znA = (zA * rsA2 + nmA2) * g2[s] + be2[s];
            f32x2 znB = (zB * rsB2 + nmB2) * g2[s] + be2[s];
            f32x2 uaA = znA * (znA * znA * C2v + C1v);
            f32x2 uaB = znB * (znB * znB * C2v + C1v);
            f32x2 eA, eB;
            eA.x = __builtin_amdgcn_exp2f(-uaA.x);
            eA.y = __builtin_amdgcn_exp2f(-uaA.y);
            eB.x = __builtin_amdgcn_exp2f(-uaB.x);
            eB.y = __builtin_amdgcn_exp2f(-uaB.y);
            f32x2 qA = eA + one2;
            f32x2 qB = eB + one2;
            f32x2 rrA, rrB;
            rrA.x = __builtin_amdgcn_rcpf(qA.x);
            rrA.y = __builtin_amdgcn_rcpf(qA.y);
            rrB.x = __builtin_amdgcn_rcpf(qB.x);
            rrB.y = __builtin_amdgcn_rcpf(qB.y);
            f32x2 nwA = znA * w22[s];
            f32x2 nwB = znB * w22[s];
            dA = nwA * rrA + dA;
            dB = nwB * rrB + dB;
        }
        float dotA = dA.x + dA.y;
        float dotB = dB.x + dB.y;
#pragma unroll
        for (int m = 1; m < 64; m <<= 1) {
            dotA += __shfl_xor(dotA, m);
            dotB += __shfl_xor(dotB, m);
        }
        if (lane == 0) {
            float da = (dotA + b2v) - spd[(size_t)i * NN + ja];
            float db = (dotB + b2v) - spd[(size_t)i * NN + jb];
            bacc += da * da + db * db;
        }
    }
    if (lane == 0) partials[i * 32 + y] = bacc;
}

// ---------------------------------------------------------------- final loss reduce (single block)
__global__ __launch_bounds__(256) void k_out(const float* __restrict__ rec_part,
        const float* __restrict__ spd_part, float* __restrict__ out) {
    __shared__ float rA[4], rB[4];
    int tid = threadIdx.x;
    float sp = 0.f, rc = 0.f;
    for (int t = tid; t < 32 * NN; t += 256) sp += spd_part[t];
    for (int t = tid; t < 2 * NMASK; t += 256) rc += rec_part[t];
#pragma unroll
    for (int m = 1; m < 64; m <<= 1) { sp += __shfl_xor(sp, m); rc += __shfl_xor(rc, m); }
    int wave = tid >> 6, lane = tid & 63;
    if (lane == 0) { rA[wave] = sp; rB[wave] = rc; }
    __syncthreads();
    if (tid == 0) {
        float SP = rA[0] + rA[1] + rA[2] + rA[3];
        float RC = rB[0] + rB[1] + rB[2] + rB[3];
        out[0] = RC + 0.5f * (SP * (1.f / ((float)NN * (float)NN)));
    }
}

// ================================================================ host
extern "C" void kernel_launch(void* const* d_in, const int* in_sizes, int n_in,
                              void* d_out, int out_size, void* d_ws, size_t ws_size,
                              hipStream_t stream) {
    const float* feat_text = (const float*)d_in[0];
    const float* feat_image = (const float*)d_in[1];
    const float* spd_matrix = (const float*)d_in[2];
    const int*   src       = (const int*)d_in[3];
    const int*   dst       = (const int*)d_in[4];
    const int*   mask_idx  = (const int*)d_in[5];
    const float* mask_token = (const float*)d_in[6];
    const float* gate_W = (const float*)d_in[7];
    const float* gate_b = (const float*)d_in[8];
    const float* exp_W1 = (const float*)d_in[9];
    const float* exp_b1 = (const float*)d_in[10];
    const float* exp_g1 = (const float*)d_in[11];
    const float* exp_be1 = (const float*)d_in[12];
    const float* exp_W2 = (const float*)d_in[13];
    const float* exp_b2 = (const float*)d_in[14];
    const float* gat_W  = (const float*)d_in[15];
    const float* gat_al = (const float*)d_in[16];
    const float* gat_ar = (const float*)d_in[17];
    const float* gat_b  = (const float*)d_in[18];
    const float* dec_W1 = (const float*)d_in[19];
    const float* dec_b1 = (const float*)d_in[20];
    const float* dec_g  = (const float*)d_in[21];
    const float* dec_be = (const float*)d_in[22];
    const float* dec_W2 = (const float*)d_in[23];
    const float* dec_b2 = (const float*)d_in[24];
    const float* spd_W1 = (const float*)d_in[25];
    const float* spd_b1 = (const float*)d_in[26];
    const float* spd_g  = (const float*)d_in[27];
    const float* spd_be = (const float*)d_in[28];
    const float* spd_W2 = (const float*)d_in[29];
    const float* spd_b2 = (const float*)d_in[30];
    (void)in_sizes; (void)n_in; (void)ws_size; (void)out_size;

    float* ws = (float*)d_ws;
    size_t off = 0;
    auto alloc = [&](size_t nfl) { float* p = ws + off; off += (nfl + 3) & ~(size_t)3; return p; };
    float* hA   = alloc((size_t)NN * HD);
    float* hB   = alloc((size_t)NN * HD);
    float* t1   = alloc((size_t)NN * TOPK * HD);
    float* eo   = alloc((size_t)NN * TOPK * HD);
    float* fbuf = alloc((size_t)NN * GATB);
    float* pab  = alloc((size_t)2 * NN * HD);
    float* cross = alloc((size_t)NN * NN);
    float* Svec = alloc(2 * NN);
    float* Qvec = alloc(2 * NN);
    float* topw = alloc(NN * TOPK);
    float* rec_part = alloc(2 * NMASK + 4);
    float* spd_part = alloc(32 * NN);
    int* topi    = (int*)alloc(NN * TOPK);
    int* ecnt    = (int*)alloc(16);
    int* estart  = (int*)alloc(16);
    int* posArr  = (int*)alloc(NN * TOPK);
    int* eofpos  = (int*)alloc(NN * TOPK);
    int* rowlist = (int*)alloc(NN * TOPK);
    int* dec_rs  = (int*)alloc(4);
    int* nstart  = (int*)alloc(NN + 4);
    int* esorted = (int*)alloc(EE);
    int* counts    = (int*)alloc((size_t)NCHUNK * NN);
    int* chunkbase = (int*)alloc((size_t)NCHUNK * NN);
    ushort* xm_bf  = (ushort*)alloc((size_t)NN * HD / 2);
    ushort* eh_bf  = (ushort*)alloc((size_t)NN * TOPK * HD / 2);
    ushort* hA_bf  = (ushort*)alloc((size_t)NN * HD / 2);
    ushort* hB_bf  = (ushort*)alloc((size_t)NN * HD / 2);
    ushort* pp_bf  = (ushort*)alloc((size_t)2 * NN * HD / 2);
    ushort* expW1t = (ushort*)alloc((size_t)NEXPERT * HD * HD / 2);
    ushort* expW2t = (ushort*)alloc((size_t)NEXPERT * HD * HD / 2);
    ushort* gatWt  = (ushort*)alloc((size_t)NLAYER * GATB * HD / 2);
    ushort* spdW1t = (ushort*)alloc((size_t)2 * HD * HD / 2);
    ushort* decW1t = (ushort*)alloc((size_t)2 * HD * HD / 2);
    ushort* decW2t = (ushort*)alloc((size_t)2 * HD * HD / 2);

    // weight transposes (small-LDS body) + separate el/er projection kernel
    k_transpose_all<<<dim3(9792), dim3(256), 0, stream>>>(
        exp_W1, exp_W2, gat_W, spd_W1, dec_W1, dec_W2,
        expW1t, expW2t, gatWt, spdW1t, decW1t, decW2t);
    k_elproj<<<dim3(36), dim3(256), 0, stream>>>(gat_W, gat_al, gat_ar, gatWt);

    // xm+gate (+edge histogram)
    k_xm_gate_hist<<<dim3(NN + NCHUNK), dim3(256), 0, stream>>>(
        feat_text, feat_image, mask_idx, mask_token, xm_bf, gate_W, gate_b, topi, topw,
        dst, counts);

    // edge scan + MoE meta fused
    k_scan_meta<<<dim3(2), dim3(NN), 0, stream>>>(
        counts, chunkbase, nstart, topi, ecnt, estart, posArr, eofpos, rowlist, dec_rs);
    k_rank2<<<dim3(NCHUNK), dim3(256), 0, stream>>>(dst, chunkbase, nstart, esorted);

    // experts
    k_mfma_gemm<<<dim3(HD / 64, 12, NEXPERT), dim3(256), 0, stream>>>(
        xm_bf, expW1t, t1, 0, HD, HD, HD, HD, (long)HD * HD, 0, rowlist, ecnt, estart);
    k_ln_gelu<<<dim3(NN * TOPK), dim3(256), 0, stream>>>(t1, eh_bf, exp_b1, exp_g1, exp_be1, eofpos);
    k_mfma_gemm<<<dim3(HD / 64, 12, NEXPERT), dim3(256), 0, stream>>>(
        eh_bf, expW2t, eo, 0, HD, HD, HD, HD, (long)HD * HD, 0, nullptr, ecnt, estart);
    k_combine_moe<<<dim3(NN), dim3(256), 0, stream>>>(eo, exp_b2, topi, topw, posArr, hA, hA_bf);

    // GAT layers (el/er computed inside the GEMM via appended B rows)
    float* hcur = hA; float* hnxt = hB;
    ushort* hcur_bf = hA_bf; ushort* hnxt_bf = hB_bf;
    for (int l = 0; l < NLAYER; l++) {
        k_mfma_gemm<<<dim3(GATB / 64, NN / 64, 1), dim3(256), 0, stream>>>(
            hcur_bf, gatWt + (size_t)l * GATB * HD, fbuf,
            NN, GATB, HD, HD, GATB, 0, 0, nullptr, nullptr, nullptr);
        k_gat_agg<<<dim3(NN), dim3(256), 0, stream>>>(
            fbuf, src, esorted, nstart, gat_b + (size_t)l * NHEADS * HD, hnxt, hnxt_bf,
            (l == NLAYER - 1) ? (float*)d_out : nullptr);
        float* t = hcur; hcur = hnxt; hnxt = t;
        ushort* tb = hcur_bf; hcur_bf = hnxt_bf; hnxt_bf = tb;
    }
    ushort* hfin_bf = hcur_bf;

    // dual GEMM 1: SPD projections (z=0,1) + decoder W1 (z=2,3 with row gather)
    k_mfma_dual<<<dim3(HD / 64, NN / 64, 4), dim3(256), 0, stream>>>(
        hfin_bf, spdW1t, pab, NN, HD, HD, HD, (long)HD * HD, (long)NN * HD,
        nullptr, nullptr, 2,
        hfin_bf, decW1t, t1, NMASK, HD, HD, HD, (long)HD * HD, (long)NMASK * HD,
        mask_idx, nullptr);

    // fused: SPD prep (fold b1, stats, bf16) + decoder LN+GELU
    k_lndec_prep<<<dim3(2 * NN + 2 * NMASK), dim3(256), 0, stream>>>(
        pab, spd_b1, pp_bf, Svec, Qvec, t1, eh_bf, dec_b1, dec_g, dec_be);

    // dual GEMM 2: decoder W2 (z=0,1) + SPD cross (z=2)
    k_mfma_dual<<<dim3(HD / 64, NN / 64, 3), dim3(256), 0, stream>>>(
        eh_bf, decW2t, eo, NMASK, HD, HD, HD, (long)HD * HD, 0,
        nullptr, dec_rs, 2,
        pp_bf, pp_bf + (size_t)NN * HD, cross, NN, NN, HD, NN, 0, 0,
        nullptr, nullptr);

    // SPD loss (packed) + cosine recon-loss blocks (y==8)
    k_spd2<<<dim3(NN, 9), dim3(256), 0, stream>>>(
        pab, Svec, Qvec, cross, spd_g, spd_be, spd_W2, spd_b2, spd_matrix, spd_part,
        eo, dec_b2, mask_idx, feat_text, feat_image, rec_part);

    // final loss reduce
    k_out<<<dim3(1), dim3(256), 0, stream>>>(rec_part, spd_part, (float*)d_out);
}

// Round 15
// 295.967 us; speedup vs baseline: 1.0609x; 1.0481x over previous
//
#include <hip/hip_runtime.h>
#include <hip/hip_bf16.h>
#include <math.h>

#define NN 384
#define HD 768
#define EE 12288
#define NCHUNK (EE / 256)
#define NEXPERT 8
#define TOPK 2
#define NLAYER 3
#define NHEADS 4
#define NMASK 38

typedef __attribute__((ext_vector_type(8))) short short8v;
typedef __attribute__((ext_vector_type(4))) float f32x4;
typedef __attribute__((ext_vector_type(2))) float f32x2;
typedef __attribute__((ext_vector_type(4))) int int4v;

__device__ __forceinline__ float gelu_f(float x) {
    return x * 0.5f * (1.f + erff(x * 0.70710678118654752440f));
}

__device__ __forceinline__ ushort f2bf(float x) {
    unsigned u = __float_as_uint(x);
    u += 0x7fffu + ((u >> 16) & 1u);
    return (ushort)(u >> 16);
}

// ---------------------------------------------------------------- fused prologue:
// blocks [0,9792): weight transposes f32->bf16 (64x32 tiles)
// blocks [9792, 9792+NN): xm+mask+bf16 and gate top-2
// blocks [9792+NN, ...): edge histogram chunks
__global__ __launch_bounds__(256) void k_pre(
        const float* __restrict__ w1, const float* __restrict__ w2,
        const float* __restrict__ gw, const float* __restrict__ sw,
        const float* __restrict__ dw1, const float* __restrict__ dw2,
        ushort* __restrict__ o1, ushort* __restrict__ o2, ushort* __restrict__ og,
        ushort* __restrict__ os, ushort* __restrict__ od1, ushort* __restrict__ od2,
        const float* __restrict__ a, const float* __restrict__ b,
        const int* __restrict__ mask_idx, const float* __restrict__ mt,
        ushort* __restrict__ xm_bf, const float* __restrict__ gW,
        const float* __restrict__ gb, int* __restrict__ topi, float* __restrict__ topw,
        const int* __restrict__ dst, int* __restrict__ counts) {
    __shared__ __align__(16) float smem[2112];   // 8448 B union
    int bI = blockIdx.x;
    int tid = threadIdx.x;
    if (bI >= 9792 + NN) {
        // edge histogram chunk
        int* h = (int*)smem;
        int c = bI - 9792 - NN;
        for (int i = tid; i < NN; i += 256) h[i] = 0;
        __syncthreads();
        atomicAdd(&h[dst[c * 256 + tid]], 1);
        __syncthreads();
        for (int i = tid; i < NN; i += 256) counts[c * NN + i] = h[i];
        return;
    }
    if (bI >= 9792) {
        // xm + gate
        int n = bI - 9792;
        float* xs = smem;                 // [HD]
        float* logits = smem + HD;        // [8]
        int* ismp = (int*)(smem + HD + 8);
        if (tid == 0) *ismp = 0;
        __syncthreads();
        if (tid < NMASK && mask_idx[tid] == n) *ismp = 1;
        __syncthreads();
        int ism = *ismp;
#pragma unroll
        for (int r = 0; r < 3; r++) {
            int j = r * 256 + tid;
            float v = ism ? mt[j] : 0.5f * (a[(size_t)n * HD + j] + b[(size_t)n * HD + j]);
            xs[j] = v;
            xm_bf[(size_t)n * HD + j] = f2bf(v);
        }
        __syncthreads();
        int grp = tid >> 5;
        int l32 = tid & 31;
        float p = 0.f;
        for (int dd = l32; dd < HD; dd += 32) p += xs[dd] * gW[dd * NEXPERT + grp];
#pragma unroll
        for (int m = 1; m < 32; m <<= 1) p += __shfl_xor(p, m, 32);
        if (l32 == 0) logits[grp] = p + gb[grp];
        __syncthreads();
        if (tid == 0) {
            float mx = logits[0];
#pragma unroll
            for (int e = 1; e < NEXPERT; e++) mx = fmaxf(mx, logits[e]);
            float sm[NEXPERT]; float s = 0.f;
#pragma unroll
            for (int e = 0; e < NEXPERT; e++) { sm[e] = expf(logits[e] - mx); s += sm[e]; }
#pragma unroll
            for (int e = 0; e < NEXPERT; e++) sm[e] /= s;
            int i0 = 0; float b0 = sm[0];
#pragma unroll
            for (int e = 1; e < NEXPERT; e++) if (sm[e] > b0) { b0 = sm[e]; i0 = e; }
            int i1 = -1; float b1v = -1.f;
#pragma unroll
            for (int e = 0; e < NEXPERT; e++) if (e != i0 && sm[e] > b1v) { b1v = sm[e]; i1 = e; }
            float ssum = b0 + b1v;
            topi[n * 2] = i0; topi[n * 2 + 1] = i1;
            topw[n * 2] = b0 / ssum; topw[n * 2 + 1] = b1v / ssum;
        }
        return;
    }
    // weight transpose tile
    const float* src; ushort* dstp; int N, loc, tilesX;
    if (bI < 2304)      { src = w1;  dstp = o1;  N = HD;     loc = bI;        tilesX = 24; }
    else if (bI < 4608) { src = w2;  dstp = o2;  N = HD;     loc = bI - 2304; tilesX = 24; }
    else if (bI < 8064) { src = gw;  dstp = og;  N = 4 * HD; loc = bI - 4608; tilesX = 96; }
    else if (bI < 8640) { src = sw;  dstp = os;  N = HD;     loc = bI - 8064; tilesX = 24; }
    else if (bI < 9216) { src = dw1; dstp = od1; N = HD;     loc = bI - 8640; tilesX = 24; }
    else                { src = dw2; dstp = od2; N = HD;     loc = bI - 9216; tilesX = 24; }
    const int K = HD;
    int tilesPerZ = tilesX * 12;
    int z = loc / tilesPerZ;
    int rem = loc - z * tilesPerZ;
    int ty = rem / tilesX, tx = rem - ty * tilesX;
    const float* inz = src + (size_t)z * K * N;
    ushort* outz = dstp + (size_t)z * K * N;
    int n0 = tx * 32, k0 = ty * 64;

    float (*t)[33] = reinterpret_cast<float (*)[33]>(smem);
    int r = tid >> 2, c8 = (tid & 3) * 8;
    const float* ip = inz + (size_t)(k0 + r) * N + n0 + c8;
    float4 va = *reinterpret_cast<const float4*>(ip);
    float4 vb = *reinterpret_cast<const float4*>(ip + 4);
    t[r][c8 + 0] = va.x; t[r][c8 + 1] = va.y; t[r][c8 + 2] = va.z; t[r][c8 + 3] = va.w;
    t[r][c8 + 4] = vb.x; t[r][c8 + 5] = vb.y; t[r][c8 + 6] = vb.z; t[r][c8 + 7] = vb.w;
    __syncthreads();
    int nn = tid >> 3;
    int kk = (tid & 7) * 8;
    uint4 o;
    uint pk[4];
#pragma unroll
    for (int q = 0; q < 4; q++) {
        ushort lo = f2bf(t[kk + 2 * q][nn]);
        ushort hi = f2bf(t[kk + 2 * q + 1][nn]);
        pk[q] = (uint)lo | ((uint)hi << 16);
    }
    o.x = pk[0]; o.y = pk[1]; o.z = pk[2]; o.w = pk[3];
    *reinterpret_cast<uint4*>(outz + (size_t)(n0 + nn) * K + k0 + kk) = o;
}

// ---------------------------------------------------------------- fused scan (edges) + MoE meta
__global__ __launch_bounds__(NN) void k_scan_meta(const int* __restrict__ counts,
        int* __restrict__ chunkbase, int* __restrict__ nstart,
        const int* __restrict__ topi, int* __restrict__ ecnt, int* __restrict__ estart,
        int* __restrict__ posArr, int* __restrict__ eofpos, int* __restrict__ rowlist,
        int* __restrict__ dec_rs) {
    int tid = threadIdx.x;
    if (blockIdx.x == 0) {
        __shared__ int tot[NN];
        int n = tid;
        int s = 0;
        for (int c = 0; c < NCHUNK; c++) { chunkbase[c * NN + n] = s; s += counts[c * NN + n]; }
        tot[n] = s;
        __syncthreads();
        for (int off = 1; off < NN; off <<= 1) {
            int v = tot[n];
            int add = (n >= off) ? tot[n - off] : 0;
            __syncthreads();
            tot[n] = v + add;
            __syncthreads();
        }
        nstart[n + 1] = tot[n];
        if (n == 0) nstart[0] = 0;
        return;
    }
    __shared__ int ti[NN * TOPK];
    __shared__ int cnt[NEXPERT];
    __shared__ int est[NEXPERT + 1];
    if (tid < NEXPERT) cnt[tid] = 0;
    __syncthreads();
    for (int a = tid; a < NN * TOPK; a += NN) ti[a] = topi[a];
    __syncthreads();
    for (int a = tid; a < NN * TOPK; a += NN) atomicAdd(&cnt[ti[a]], 1);
    __syncthreads();
    if (tid == 0) {
        int s = 0;
        for (int e = 0; e < NEXPERT; e++) { est[e] = s; s += cnt[e]; }
        est[NEXPERT] = s;
        dec_rs[0] = 0; dec_rs[1] = NMASK;
    }
    __syncthreads();
    if (tid < NEXPERT) { ecnt[tid] = cnt[tid]; estart[tid] = est[tid]; }
    if (tid == 0) estart[NEXPERT] = est[NEXPERT];
    for (int a = tid; a < NN * TOPK; a += NN) {
        int e = ti[a]; int rank = 0;
        for (int a2 = 0; a2 < a; a2++) rank += (ti[a2] == e) ? 1 : 0;
        int p = est[e] + rank;
        posArr[a] = p; eofpos[p] = e; rowlist[p] = a >> 1;
    }
}

__global__ __launch_bounds__(256) void k_rank2(const int* __restrict__ dst,
        const int* __restrict__ chunkbase, const int* __restrict__ nstart,
        int* __restrict__ esorted) {
    __shared__ int ds[256];
    int c = blockIdx.x;
    int e = c * 256 + threadIdx.x;
    int d = dst[e];
    ds[threadIdx.x] = d;
    __syncthreads();
    int r = 0;
    for (int i = 0; i < threadIdx.x; i++) r += (ds[i] == d) ? 1 : 0;
    esorted[nstart[d] + chunkbase[c * NN + d] + r] = e;
}

// ---------------------------------------------------------------- bf16 MFMA GEMM (pipelined body)
__device__ __forceinline__ short8v ldfrag(const ushort* s, int r, int kb) {
    int c = kb ^ (r & 7);
    return *reinterpret_cast<const short8v*>(s + r * 64 + c * 8);
}

__device__ __forceinline__ void gemm_body(
        const ushort* __restrict__ A, const ushort* __restrict__ Bt, float* __restrict__ C,
        int M, int Ncol, int K, int lda, int ldc, long strideBt, long strideC,
        const int* __restrict__ rowsA, const int* __restrict__ Ms,
        const int* __restrict__ rowStarts, int z, ushort* Asm, ushort* Bsm) {
    int Meff = Ms ? Ms[z] : M;
    int row0 = blockIdx.y * 64;
    if (row0 >= Meff) return;
    int col0 = blockIdx.x * 64;
    if (col0 >= Ncol) return;
    int rowbase = rowStarts ? rowStarts[z] : 0;
    const ushort* Btz = Bt + (size_t)z * strideBt;
    float* Cz = C + (size_t)rowbase * ldc + (size_t)z * strideC;
    const int* rz = rowsA ? (rowsA + rowbase) : nullptr;

    int tid = threadIdx.x;
    int w = tid >> 6, lane = tid & 63;
    int wr = w >> 1, wc = w & 1;
    int l15 = lane & 15, lq = lane >> 4;

    int r0s = tid >> 3, c0s = tid & 7;
    int cs0 = c0s ^ (r0s & 7);
    int r1s = r0s + 32;
    int cs1 = c0s ^ (r1s & 7);
    int grow0 = row0 + r0s, grow1 = row0 + r1s;
    bool ok0 = grow0 < Meff, ok1 = grow1 < Meff;
    int srow0 = ok0 ? (rz ? rz[grow0] : rowbase + grow0) : (rz ? rz[0] : rowbase);
    int srow1 = ok1 ? (rz ? rz[grow1] : rowbase + grow1) : (rz ? rz[0] : rowbase);
    const ushort* aP0 = A + (size_t)srow0 * lda + c0s * 8;
    const ushort* aP1 = A + (size_t)srow1 * lda + c0s * 8;
    const ushort* bP0 = Btz + (size_t)(col0 + r0s) * K + c0s * 8;
    const ushort* bP1 = Btz + (size_t)(col0 + r1s) * K + c0s * 8;
    ushort* asm0 = &Asm[r0s * 64 + cs0 * 8];
    ushort* asm1 = &Asm[r1s * 64 + cs1 * 8];
    ushort* bsm0 = &Bsm[r0s * 64 + cs0 * 8];
    ushort* bsm1 = &Bsm[r1s * 64 + cs1 * 8];
    const int4v z4 = (int4v){0, 0, 0, 0};

    f32x4 acc[2][2];
#pragma unroll
    for (int i = 0; i < 2; i++)
#pragma unroll
        for (int j = 0; j < 2; j++) acc[i][j] = (f32x4){0.f, 0.f, 0.f, 0.f};

    int4v ta0 = *reinterpret_cast<const int4v*>(aP0);
    int4v ta1 = *reinterpret_cast<const int4v*>(aP1);
    int4v av0 = ok0 ? ta0 : z4;
    int4v av1 = ok1 ? ta1 : z4;
    int4v bv0 = *reinterpret_cast<const int4v*>(bP0);
    int4v bv1 = *reinterpret_cast<const int4v*>(bP1);

    for (int k0 = 0; k0 < K; k0 += 64) {
        *reinterpret_cast<int4v*>(asm0) = av0;
        *reinterpret_cast<int4v*>(asm1) = av1;
        *reinterpret_cast<int4v*>(bsm0) = bv0;
        *reinterpret_cast<int4v*>(bsm1) = bv1;
        __syncthreads();
        int kn = k0 + 64;
        if (kn < K) {
            int4v na0 = *reinterpret_cast<const int4v*>(aP0 + kn);
            int4v na1 = *reinterpret_cast<const int4v*>(aP1 + kn);
            av0 = ok0 ? na0 : z4;
            av1 = ok1 ? na1 : z4;
            bv0 = *reinterpret_cast<const int4v*>(bP0 + kn);
            bv1 = *reinterpret_cast<const int4v*>(bP1 + kn);
        }
#pragma unroll
        for (int ks = 0; ks < 2; ks++) {
            int kb = ks * 4 + lq;
            short8v a0 = ldfrag(Asm, wr * 32 + l15, kb);
            short8v a1 = ldfrag(Asm, wr * 32 + 16 + l15, kb);
            short8v b0 = ldfrag(Bsm, wc * 32 + l15, kb);
            short8v b1 = ldfrag(Bsm, wc * 32 + 16 + l15, kb);
            acc[0][0] = __builtin_amdgcn_mfma_f32_16x16x32_bf16(a0, b0, acc[0][0], 0, 0, 0);
            acc[0][1] = __builtin_amdgcn_mfma_f32_16x16x32_bf16(a0, b1, acc[0][1], 0, 0, 0);
            acc[1][0] = __builtin_amdgcn_mfma_f32_16x16x32_bf16(a1, b0, acc[1][0], 0, 0, 0);
            acc[1][1] = __builtin_amdgcn_mfma_f32_16x16x32_bf16(a1, b1, acc[1][1], 0, 0, 0);
        }
        __syncthreads();
    }
#pragma unroll
    for (int ai = 0; ai < 2; ai++)
#pragma unroll
        for (int bi = 0; bi < 2; bi++) {
            int rbase = row0 + wr * 32 + ai * 16 + (lq << 2);
            int cc = col0 + wc * 32 + bi * 16 + l15;
#pragma unroll
            for (int r = 0; r < 4; r++) {
                int rr = rbase + r;
                if (rr < Meff) Cz[(size_t)rr * ldc + cc] = acc[ai][bi][r];
            }
        }
}

__global__ __launch_bounds__(256) void k_mfma_gemm(
        const ushort* __restrict__ A, const ushort* __restrict__ Bt, float* __restrict__ C,
        int M, int Ncol, int K, int lda, int ldc, long strideBt, long strideC,
        const int* __restrict__ rowsA, const int* __restrict__ Ms,
        const int* __restrict__ rowStarts) {
    __shared__ ushort Asm[64 * 64];
    __shared__ ushort Bsm[64 * 64];
    gemm_body(A, Bt, C, M, Ncol, K, lda, ldc, strideBt, strideC, rowsA, Ms, rowStarts,
              blockIdx.z, Asm, Bsm);
}

__global__ __launch_bounds__(256) void k_mfma_dual(
        const ushort* __restrict__ A0, const ushort* __restrict__ Bt0, float* __restrict__ C0,
        int M0, int Nc0, int lda0, int ldc0, long sBt0, long sC0,
        const int* __restrict__ rows0, const int* __restrict__ rs0, int nz0,
        const ushort* __restrict__ A1, const ushort* __restrict__ Bt1, float* __restrict__ C1,
        int M1, int Nc1, int lda1, int ldc1, long sBt1, long sC1,
        const int* __restrict__ rows1, const int* __restrict__ rs1) {
    __shared__ ushort Asm[64 * 64];
    __shared__ ushort Bsm[64 * 64];
    int z = blockIdx.z;
    if (z < nz0)
        gemm_body(A0, Bt0, C0, M0, Nc0, HD, lda0, ldc0, sBt0, sC0, rows0, nullptr, rs0,
                  z, Asm, Bsm);
    else
        gemm_body(A1, Bt1, C1, M1, Nc1, HD, lda1, ldc1, sBt1, sC1, rows1, nullptr, rs1,
                  z - nz0, Asm, Bsm);
}

// ---------------------------------------------------------------- expert LN+GELU -> bf16
__global__ __launch_bounds__(256) void k_ln_gelu(const float* __restrict__ t1,
        ushort* __restrict__ ehb, const float* __restrict__ b1, const float* __restrict__ g,
        const float* __restrict__ be, const int* __restrict__ eofpos) {
    int row = blockIdx.x;
    int e = eofpos[row];
    int tid = threadIdx.x;
    __shared__ float rA[4], rB[4];
    float v[3]; float s1 = 0.f, s2 = 0.f;
#pragma unroll
    for (int r = 0; r < 3; r++) {
        int c = r * 256 + tid;
        float x = t1[(size_t)row * HD + c] + b1[e * HD + c];
        v[r] = x; s1 += x; s2 += x * x;
    }
#pragma unroll
    for (int m = 1; m < 64; m <<= 1) { s1 += __shfl_xor(s1, m); s2 += __shfl_xor(s2, m); }
    int wave = tid >> 6, lane = tid & 63;
    if (lane == 0) { rA[wave] = s1; rB[wave] = s2; }
    __syncthreads();
    float S1 = rA[0] + rA[1] + rA[2] + rA[3];
    float S2 = rB[0] + rB[1] + rB[2] + rB[3];
    float mean = S1 * (1.f / HD);
    float var = S2 * (1.f / HD) - mean * mean;
    float rstd = rsqrtf(var + 1e-5f);
#pragma unroll
    for (int r = 0; r < 3; r++) {
        int c = r * 256 + tid;
        float zn = (v[r] - mean) * rstd * g[e * HD + c] + be[e * HD + c];
        ehb[(size_t)row * HD + c] = f2bf(gelu_f(zn));
    }
}

__global__ void k_combine_moe(const float* __restrict__ eo, const float* __restrict__ b2,
        const int* __restrict__ topi, const float* __restrict__ topw,
        const int* __restrict__ posArr, float* __restrict__ h, ushort* __restrict__ hb) {
    int n = blockIdx.x;
    int tid = threadIdx.x;
    int e0 = topi[n * 2], e1 = topi[n * 2 + 1];
    float w0 = topw[n * 2], w1 = topw[n * 2 + 1];
    int p0 = posArr[n * 2], p1 = posArr[n * 2 + 1];
    for (int j = tid; j < HD; j += 256) {
        float v0 = eo[(size_t)p0 * HD + j] + b2[e0 * HD + j];
        float v1 = eo[(size_t)p1 * HD + j] + b2[e1 * HD + j];
        float hv = w0 * v0 + w1 * v1;
        h[(size_t)n * HD + j] = hv;
        hb[(size_t)n * HD + j] = f2bf(hv);
    }
}

// ---------------------------------------------------------------- GAT
__global__ __launch_bounds__(256) void k_el_er(const float* __restrict__ f,
        const float* __restrict__ al, const float* __restrict__ ar,
        float* __restrict__ el, float* __restrict__ er) {
    int n = blockIdx.x;
    int hd = threadIdx.x >> 6, lane = threadIdx.x & 63;
    const float* fr = f + ((size_t)n * NHEADS + hd) * HD;
    float pl = 0.f, pr = 0.f;
    for (int j = lane; j < HD; j += 64) {
        float fv = fr[j];
        pl += fv * al[hd * HD + j];
        pr += fv * ar[hd * HD + j];
    }
#pragma unroll
    for (int m = 1; m < 64; m <<= 1) { pl += __shfl_xor(pl, m); pr += __shfl_xor(pr, m); }
    if (lane == 0) { el[n * NHEADS + hd] = pl; er[n * NHEADS + hd] = pr; }
}

__global__ __launch_bounds__(256) void k_gat_agg(const float* __restrict__ f,
        const float* __restrict__ el, const float* __restrict__ er,
        const int* __restrict__ src, const int* __restrict__ esorted,
        const int* __restrict__ nstart, const float* __restrict__ gb,
        float* __restrict__ hout, ushort* __restrict__ hb, float* __restrict__ outp) {
    int n = blockIdx.x;
    int s0 = nstart[n], cnt = nstart[n + 1] - s0;
    int tid = threadIdx.x;
    __shared__ float red[4][NHEADS];
    __shared__ float emax_s[NHEADS], den_s[NHEADS];
    __shared__ float alpha_s[256][NHEADS];
    __shared__ int sn_s[256];
    float ern[NHEADS];
#pragma unroll
    for (int hd = 0; hd < NHEADS; hd++) ern[hd] = er[n * NHEADS + hd];
    int wave = tid >> 6, lane = tid & 63;

    float mx[NHEADS] = { -1e30f, -1e30f, -1e30f, -1e30f };
    for (int t = tid; t < cnt; t += 256) {
        int e = esorted[s0 + t]; int sn = src[e];
#pragma unroll
        for (int hd = 0; hd < NHEADS; hd++) {
            float v = el[sn * NHEADS + hd] + ern[hd];
            v = (v >= 0.f) ? v : 0.2f * v;
            mx[hd] = fmaxf(mx[hd], v);
        }
    }
#pragma unroll
    for (int hd = 0; hd < NHEADS; hd++) {
#pragma unroll
        for (int m = 1; m < 64; m <<= 1) mx[hd] = fmaxf(mx[hd], __shfl_xor(mx[hd], m));
    }
    if (lane == 0) { for (int hd = 0; hd < NHEADS; hd++) red[wave][hd] = mx[hd]; }
    __syncthreads();
    if (tid == 0) {
#pragma unroll
        for (int hd = 0; hd < NHEADS; hd++)
            emax_s[hd] = fmaxf(fmaxf(red[0][hd], red[1][hd]), fmaxf(red[2][hd], red[3][hd]));
    }
    __syncthreads();
    float sm[NHEADS] = { 0.f, 0.f, 0.f, 0.f };
    for (int t = tid; t < cnt; t += 256) {
        int e = esorted[s0 + t]; int sn = src[e];
#pragma unroll
        for (int hd = 0; hd < NHEADS; hd++) {
            float v = el[sn * NHEADS + hd] + ern[hd];
            v = (v >= 0.f) ? v : 0.2f * v;
            sm[hd] += expf(v - emax_s[hd]);
        }
    }
#pragma unroll
    for (int hd = 0; hd < NHEADS; hd++) {
#pragma unroll
        for (int m = 1; m < 64; m <<= 1) sm[hd] += __shfl_xor(sm[hd], m);
    }
    __syncthreads();
    if (lane == 0) { for (int hd = 0; hd < NHEADS; hd++) red[wave][hd] = sm[hd]; }
    __syncthreads();
    if (tid == 0) {
#pragma unroll
        for (int hd = 0; hd < NHEADS; hd++)
            den_s[hd] = red[0][hd] + red[1][hd] + red[2][hd] + red[3][hd];
    }
    __syncthreads();
    float acc[NHEADS][3] = {};
    for (int c0 = 0; c0 < cnt; c0 += 256) {
        int t = c0 + tid;
        if (t < cnt) {
            int e = esorted[s0 + t]; int sn = src[e];
            sn_s[tid] = sn;
#pragma unroll
            for (int hd = 0; hd < NHEADS; hd++) {
                float v = el[sn * NHEADS + hd] + ern[hd];
                v = (v >= 0.f) ? v : 0.2f * v;
                alpha_s[tid][hd] = expf(v - emax_s[hd]) / fmaxf(den_s[hd], 1e-9f);
            }
        }
        __syncthreads();
        int cm = cnt - c0; if (cm > 256) cm = 256;
        for (int i = 0; i < cm; i++) {
            int sn = sn_s[i];
            const float* fr = f + (size_t)sn * (NHEADS * HD);
#pragma unroll
            for (int hd = 0; hd < NHEADS; hd++) {
                float a = alpha_s[i][hd];
#pragma unroll
                for (int r = 0; r < 3; r++) acc[hd][r] += a * fr[hd * HD + r * 256 + tid];
            }
        }
        __syncthreads();
    }
#pragma unroll
    for (int r = 0; r < 3; r++) {
        int j = r * 256 + tid;
        float s = 0.f;
#pragma unroll
        for (int hd = 0; hd < NHEADS; hd++) s += acc[hd][r] + gb[hd * HD + j];
        float hv = 0.25f * s;
        hout[(size_t)n * HD + j] = hv;
        hb[(size_t)n * HD + j] = f2bf(hv);
        if (outp) outp[1 + (size_t)n * HD + j] = hv;
    }
}

// ---------------------------------------------------------------- fused: SPD prep + decoder LN
__global__ __launch_bounds__(256) void k_lndec_prep(float* __restrict__ pab,
        const float* __restrict__ b1, ushort* __restrict__ pp_bf,
        float* __restrict__ Svec, float* __restrict__ Qvec,
        const float* __restrict__ t1, ushort* __restrict__ zzb,
        const float* __restrict__ db1, const float* __restrict__ dg,
        const float* __restrict__ dbe) {
    int tid = threadIdx.x;
    int wave = tid >> 6, lane = tid & 63;
    __shared__ float rA[4], rB[4];
    if (blockIdx.x >= 2 * NN) {
        int row = blockIdx.x - 2 * NN;      // 0..75
        int d = row / NMASK;
        float v[3]; float s1 = 0.f, s2 = 0.f;
#pragma unroll
        for (int r = 0; r < 3; r++) {
            int c = r * 256 + tid;
            float x = t1[(size_t)row * HD + c] + db1[d * HD + c];
            v[r] = x; s1 += x; s2 += x * x;
        }
#pragma unroll
        for (int mm = 1; mm < 64; mm <<= 1) { s1 += __shfl_xor(s1, mm); s2 += __shfl_xor(s2, mm); }
        if (lane == 0) { rA[wave] = s1; rB[wave] = s2; }
        __syncthreads();
        float S1 = rA[0] + rA[1] + rA[2] + rA[3];
        float S2 = rB[0] + rB[1] + rB[2] + rB[3];
        float mean = S1 * (1.f / HD);
        float var = S2 * (1.f / HD) - mean * mean;
        float rstd = rsqrtf(var + 1e-5f);
#pragma unroll
        for (int r = 0; r < 3; r++) {
            int c = r * 256 + tid;
            float zn = (v[r] - mean) * rstd * dg[d * HD + c] + dbe[d * HD + c];
            zzb[(size_t)row * HD + c] = f2bf(gelu_f(zn));
        }
        return;
    }
    int r = blockIdx.x;
    bool isA = r < NN;
    float* row = pab + (size_t)r * HD;
    float vv[3]; float s1 = 0.f, s2 = 0.f;
#pragma unroll
    for (int rr = 0; rr < 3; rr++) {
        int j = rr * 256 + tid;
        float v = row[j];
        if (isA) v += b1[j];
        vv[rr] = v; s1 += v; s2 += v * v;
    }
#pragma unroll
    for (int m = 1; m < 64; m <<= 1) { s1 += __shfl_xor(s1, m); s2 += __shfl_xor(s2, m); }
    if (lane == 0) { rA[wave] = s1; rB[wave] = s2; }
#pragma unroll
    for (int rr = 0; rr < 3; rr++) {
        int j = rr * 256 + tid;
        if (isA) row[j] = vv[rr];
        pp_bf[(size_t)r * HD + j] = f2bf(vv[rr]);
    }
    __syncthreads();
    if (tid == 0) {
        Svec[r] = rA[0] + rA[1] + rA[2] + rA[3];
        Qvec[r] = rB[0] + rB[1] + rB[2] + rB[3];
    }
}

// ---------------------------------------------------------------- SPD loss (packed f32x2) + cos fused
#define GC1 2.3022085f
#define GC2 0.10294429f
__global__ __launch_bounds__(256) void k_spd2(const float* __restrict__ pab,
        const float* __restrict__ Svec, const float* __restrict__ Qvec,
        const float* __restrict__ cross, const float* __restrict__ g,
        const float* __restrict__ be, const float* __restrict__ w2,
        const float* __restrict__ b2, const float* __restrict__ spd,
        float* __restrict__ partials,
        const float* __restrict__ rec, const float* __restrict__ db2,
        const int* __restrict__ mask_idx, const float* __restrict__ ft,
        const float* __restrict__ fi, float* __restrict__ rec_part) {
    int wv = threadIdx.x >> 6, lane = threadIdx.x & 63;
    if (blockIdx.y == 8) {
        int b = blockIdx.x;
        if (b >= 2 * NMASK) return;
        int d = b / NMASK, m = b % NMASK;
        int node = mask_idx[m];
        int tid = threadIdx.x;
        __shared__ float rA[4], rB[4], rC[4];
        const float* rrow = rec + (size_t)b * HD;
        const float* orig = (d == 0 ? ft : fi) + (size_t)node * HD;
        float pro = 0.f, prr = 0.f, poo = 0.f;
#pragma unroll
        for (int r = 0; r < 3; r++) {
            int c = r * 256 + tid;
            float rv = rrow[c] + db2[d * HD + c];
            float o = orig[c];
            pro += rv * o; prr += rv * rv; poo += o * o;
        }
#pragma unroll
        for (int mm = 1; mm < 64; mm <<= 1) {
            pro += __shfl_xor(pro, mm); prr += __shfl_xor(prr, mm); poo += __shfl_xor(poo, mm);
        }
        if (lane == 0) { rA[wv] = pro; rB[wv] = prr; rC[wv] = poo; }
        __syncthreads();
        if (tid == 0) {
            float P = rA[0] + rA[1] + rA[2] + rA[3];
            float R = rB[0] + rB[1] + rB[2] + rB[3];
            float O = rC[0] + rC[1] + rC[2] + rC[3];
            float denom = fmaxf(sqrtf(R) * sqrtf(O), 1e-8f);
            float cosv = P / denom;
            float t = 1.f - cosv;
            rec_part[b] = (t * t) * (1.f / (float)NMASK);
        }
        return;
    }
    int i = blockIdx.x;
    int y = blockIdx.y * 4 + wv;     // 0..31
    const f32x2* paP = reinterpret_cast<const f32x2*>(pab + (size_t)i * HD) + lane;
    const f32x2* gP  = reinterpret_cast<const f32x2*>(g) + lane;
    const f32x2* beP = reinterpret_cast<const f32x2*>(be) + lane;
    const f32x2* wP  = reinterpret_cast<const f32x2*>(w2) + lane;
    f32x2 pa2[6], g2[6], be2[6], w22[6];
#pragma unroll
    for (int s = 0; s < 6; s++) {
        pa2[s] = paP[s * 64];
        g2[s]  = gP[s * 64];
        be2[s] = beP[s * 64];
        w22[s] = wP[s * 64];
    }
#pragma unroll
    for (int s = 0; s < 6; s++) {
        asm volatile("" : "+v"(pa2[s]), "+v"(g2[s]), "+v"(be2[s]), "+v"(w22[s]));
    }
    const f32x2 C1v = (f32x2){GC1, GC1};
    const f32x2 C2v = (f32x2){GC2, GC2};
    const f32x2 one2 = (f32x2){1.f, 1.f};
    float Sa = Svec[i], Qa = Qvec[i];
    float b2v = b2[0];
    float bacc = 0.f;
#pragma unroll
    for (int t = 0; t < 6; t++) {
        int ja = y + (2 * t) * 32;
        int jb = y + (2 * t + 1) * 32;
        const f32x2* pA = reinterpret_cast<const f32x2*>(pab + (size_t)(NN + ja) * HD) + lane;
        const f32x2* pB = reinterpret_cast<const f32x2*>(pab + (size_t)(NN + jb) * HD) + lane;
        float meanA = (Sa + Svec[NN + ja]) * (1.f / HD);
        float exA = (Qa + Qvec[NN + ja] + 2.f * cross[(size_t)i * NN + ja]) * (1.f / HD);
        float rsA = rsqrtf(exA - meanA * meanA + 1e-5f);
        float nmA = -meanA * rsA;
        float meanB = (Sa + Svec[NN + jb]) * (1.f / HD);
        float exB = (Qa + Qvec[NN + jb] + 2.f * cross[(size_t)i * NN + jb]) * (1.f / HD);
        float rsB = rsqrtf(exB - meanB * meanB + 1e-5f);
        float nmB = -meanB * rsB;
        f32x2 rsA2 = (f32x2){rsA, rsA}, nmA2 = (f32x2){nmA, nmA};
        f32x2 rsB2 = (f32x2){rsB, rsB}, nmB2 = (f32x2){nmB, nmB};
        f32x2 dA = (f32x2){0.f, 0.f}, dB = (f32x2){0.f, 0.f};
#pragma unroll
        for (int s = 0; s < 6; s++) {
            f32x2 zA = pa2[s] + pA[s * 64];
            f32x2 zB = pa2[s] + pB[s * 64];
            f32x2 znA = (zA * rsA2 + nmA2) * g2[s] + be2[s];
            f32x2 znB = (zB * rsB2 + nmB2) * g2[s] + be2[s];
            f32x2 uaA = znA * (znA * znA * C2v + C1v);
            f32x2 uaB = znB * (znB * znB * C2v + C1v);
            f32x2 eA, eB;
            eA.x = __builtin_amdgcn_exp2f(-uaA.x);
            eA.y = __builtin_amdgcn_exp2f(-uaA.y);
            eB.x = __builtin_amdgcn_exp2f(-uaB.x);
            eB.y = __builtin_amdgcn_exp2f(-uaB.y);
            f32x2 qA = eA + one2;
            f32x2 qB = eB + one2;
            f32x2 rrA, rrB;
            rrA.x = __builtin_amdgcn_rcpf(qA.x);
            rrA.y = __builtin_amdgcn_rcpf(qA.y);
            rrB.x = __builtin_amdgcn_rcpf(qB.x);
            rrB.y = __builtin_amdgcn_rcpf(qB.y);
            f32x2 nwA = znA * w22[s];
            f32x2 nwB = znB * w22[s];
            dA = nwA * rrA + dA;
            dB = nwB * rrB + dB;
        }
        float dotA = dA.x + dA.y;
        float dotB = dB.x + dB.y;
#pragma unroll
        for (int m = 1; m < 64; m <<= 1) {
            dotA += __shfl_xor(dotA, m);
            dotB += __shfl_xor(dotB, m);
        }
        if (lane == 0) {
            float da = (dotA + b2v) - spd[(size_t)i * NN + ja];
            float db = (dotB + b2v) - spd[(size_t)i * NN + jb];
            bacc += da * da + db * db;
        }
    }
    if (lane == 0) partials[i * 32 + y] = bacc;
}

// ---------------------------------------------------------------- final loss reduce (single block)
__global__ __launch_bounds__(256) void k_out(const float* __restrict__ rec_part,
        const float* __restrict__ spd_part, float* __restrict__ out) {
    __shared__ float rA[4], rB[4];
    int tid = threadIdx.x;
    float sp = 0.f, rc = 0.f;
    for (int t = tid; t < 32 * NN; t += 256) sp += spd_part[t];
    for (int t = tid; t < 2 * NMASK; t += 256) rc += rec_part[t];
#pragma unroll
    for (int m = 1; m < 64; m <<= 1) { sp += __shfl_xor(sp, m); rc += __shfl_xor(rc, m); }
    int wave = tid >> 6, lane = tid & 63;
    if (lane == 0) { rA[wave] = sp; rB[wave] = rc; }
    __syncthreads();
    if (tid == 0) {
        float SP = rA[0] + rA[1] + rA[2] + rA[3];
        float RC = rB[0] + rB[1] + rB[2] + rB[3];
        out[0] = RC + 0.5f * (SP * (1.f / ((float)NN * (float)NN)));
    }
}

// ================================================================ host
extern "C" void kernel_launch(void* const* d_in, const int* in_sizes, int n_in,
                              void* d_out, int out_size, void* d_ws, size_t ws_size,
                              hipStream_t stream) {
    const float* feat_text = (const float*)d_in[0];
    const float* feat_image = (const float*)d_in[1];
    const float* spd_matrix = (const float*)d_in[2];
    const int*   src       = (const int*)d_in[3];
    const int*   dst       = (const int*)d_in[4];
    const int*   mask_idx  = (const int*)d_in[5];
    const float* mask_token = (const float*)d_in[6];
    const float* gate_W = (const float*)d_in[7];
    const float* gate_b = (const float*)d_in[8];
    const float* exp_W1 = (const float*)d_in[9];
    const float* exp_b1 = (const float*)d_in[10];
    const float* exp_g1 = (const float*)d_in[11];
    const float* exp_be1 = (const float*)d_in[12];
    const float* exp_W2 = (const float*)d_in[13];
    const float* exp_b2 = (const float*)d_in[14];
    const float* gat_W  = (const float*)d_in[15];
    const float* gat_al = (const float*)d_in[16];
    const float* gat_ar = (const float*)d_in[17];
    const float* gat_b  = (const float*)d_in[18];
    const float* dec_W1 = (const float*)d_in[19];
    const float* dec_b1 = (const float*)d_in[20];
    const float* dec_g  = (const float*)d_in[21];
    const float* dec_be = (const float*)d_in[22];
    const float* dec_W2 = (const float*)d_in[23];
    const float* dec_b2 = (const float*)d_in[24];
    const float* spd_W1 = (const float*)d_in[25];
    const float* spd_b1 = (const float*)d_in[26];
    const float* spd_g  = (const float*)d_in[27];
    const float* spd_be = (const float*)d_in[28];
    const float* spd_W2 = (const float*)d_in[29];
    const float* spd_b2 = (const float*)d_in[30];
    (void)in_sizes; (void)n_in; (void)ws_size; (void)out_size;

    float* ws = (float*)d_ws;
    size_t off = 0;
    auto alloc = [&](size_t nfl) { float* p = ws + off; off += (nfl + 3) & ~(size_t)3; return p; };
    float* hA   = alloc((size_t)NN * HD);
    float* hB   = alloc((size_t)NN * HD);
    float* t1   = alloc((size_t)NN * TOPK * HD);
    float* eo   = alloc((size_t)NN * TOPK * HD);
    float* fbuf = alloc((size_t)NN * NHEADS * HD);
    float* el   = alloc(NN * NHEADS);
    float* er   = alloc(NN * NHEADS);
    float* pab  = alloc((size_t)2 * NN * HD);
    float* cross = alloc((size_t)NN * NN);
    float* Svec = alloc(2 * NN);
    float* Qvec = alloc(2 * NN);
    float* topw = alloc(NN * TOPK);
    float* rec_part = alloc(2 * NMASK + 4);
    float* spd_part = alloc(32 * NN);
    int* topi    = (int*)alloc(NN * TOPK);
    int* ecnt    = (int*)alloc(16);
    int* estart  = (int*)alloc(16);
    int* posArr  = (int*)alloc(NN * TOPK);
    int* eofpos  = (int*)alloc(NN * TOPK);
    int* rowlist = (int*)alloc(NN * TOPK);
    int* dec_rs  = (int*)alloc(4);
    int* nstart  = (int*)alloc(NN + 4);
    int* esorted = (int*)alloc(EE);
    int* counts    = (int*)alloc((size_t)NCHUNK * NN);
    int* chunkbase = (int*)alloc((size_t)NCHUNK * NN);
    ushort* xm_bf  = (ushort*)alloc((size_t)NN * HD / 2);
    ushort* eh_bf  = (ushort*)alloc((size_t)NN * TOPK * HD / 2);
    ushort* hA_bf  = (ushort*)alloc((size_t)NN * HD / 2);
    ushort* hB_bf  = (ushort*)alloc((size_t)NN * HD / 2);
    ushort* pp_bf  = (ushort*)alloc((size_t)2 * NN * HD / 2);
    ushort* expW1t = (ushort*)alloc((size_t)NEXPERT * HD * HD / 2);
    ushort* expW2t = (ushort*)alloc((size_t)NEXPERT * HD * HD / 2);
    ushort* gatWt  = (ushort*)alloc((size_t)NLAYER * NHEADS * HD * HD / 2);
    ushort* spdW1t = (ushort*)alloc((size_t)2 * HD * HD / 2);
    ushort* decW1t = (ushort*)alloc((size_t)2 * HD * HD / 2);
    ushort* decW2t = (ushort*)alloc((size_t)2 * HD * HD / 2);

    // fused prologue: weight transposes + xm/gate + edge histogram (one dispatch)
    k_pre<<<dim3(9792 + NN + NCHUNK), dim3(256), 0, stream>>>(
        exp_W1, exp_W2, gat_W, spd_W1, dec_W1, dec_W2,
        expW1t, expW2t, gatWt, spdW1t, decW1t, decW2t,
        feat_text, feat_image, mask_idx, mask_token, xm_bf, gate_W, gate_b, topi, topw,
        dst, counts);

    // edge scan + MoE meta fused
    k_scan_meta<<<dim3(2), dim3(NN), 0, stream>>>(
        counts, chunkbase, nstart, topi, ecnt, estart, posArr, eofpos, rowlist, dec_rs);
    k_rank2<<<dim3(NCHUNK), dim3(256), 0, stream>>>(dst, chunkbase, nstart, esorted);

    // experts
    k_mfma_gemm<<<dim3(HD / 64, 12, NEXPERT), dim3(256), 0, stream>>>(
        xm_bf, expW1t, t1, 0, HD, HD, HD, HD, (long)HD * HD, 0, rowlist, ecnt, estart);
    k_ln_gelu<<<dim3(NN * TOPK), dim3(256), 0, stream>>>(t1, eh_bf, exp_b1, exp_g1, exp_be1, eofpos);
    k_mfma_gemm<<<dim3(HD / 64, 12, NEXPERT), dim3(256), 0, stream>>>(
        eh_bf, expW2t, eo, 0, HD, HD, HD, HD, (long)HD * HD, 0, nullptr, ecnt, estart);
    k_combine_moe<<<dim3(NN), dim3(256), 0, stream>>>(eo, exp_b2, topi, topw, posArr, hA, hA_bf);

    // GAT layers
    float* hcur = hA; float* hnxt = hB;
    ushort* hcur_bf = hA_bf; ushort* hnxt_bf = hB_bf;
    for (int l = 0; l < NLAYER; l++) {
        k_mfma_gemm<<<dim3(NHEADS * HD / 64, NN / 64, 1), dim3(256), 0, stream>>>(
            hcur_bf, gatWt + (size_t)l * NHEADS * HD * HD, fbuf,
            NN, NHEADS * HD, HD, HD, NHEADS * HD, 0, 0, nullptr, nullptr, nullptr);
        k_el_er<<<dim3(NN), dim3(256), 0, stream>>>(
            fbuf, gat_al + (size_t)l * NHEADS * HD, gat_ar + (size_t)l * NHEADS * HD, el, er);
        k_gat_agg<<<dim3(NN), dim3(256), 0, stream>>>(
            fbuf, el, er, src, esorted, nstart, gat_b + (size_t)l * NHEADS * HD, hnxt, hnxt_bf,
            (l == NLAYER - 1) ? (float*)d_out : nullptr);
        float* t = hcur; hcur = hnxt; hnxt = t;
        ushort* tb = hcur_bf; hcur_bf = hnxt_bf; hnxt_bf = tb;
    }
    ushort* hfin_bf = hcur_bf;

    // dual GEMM 1: SPD projections (z=0,1) + decoder W1 (z=2,3 with row gather)
    k_mfma_dual<<<dim3(HD / 64, NN / 64, 4), dim3(256), 0, stream>>>(
        hfin_bf, spdW1t, pab, NN, HD, HD, HD, (long)HD * HD, (long)NN * HD,
        nullptr, nullptr, 2,
        hfin_bf, decW1t, t1, NMASK, HD, HD, HD, (long)HD * HD, (long)NMASK * HD,
        mask_idx, nullptr);

    // fused: SPD prep (fold b1, stats, bf16) + decoder LN+GELU
    k_lndec_prep<<<dim3(2 * NN + 2 * NMASK), dim3(256), 0, stream>>>(
        pab, spd_b1, pp_bf, Svec, Qvec, t1, eh_bf, dec_b1, dec_g, dec_be);

    // dual GEMM 2: decoder W2 (z=0,1) + SPD cross (z=2)
    k_mfma_dual<<<dim3(HD / 64, NN / 64, 3), dim3(256), 0, stream>>>(
        eh_bf, decW2t, eo, NMASK, HD, HD, HD, (long)HD * HD, 0,
        nullptr, dec_rs, 2,
        pp_bf, pp_bf + (size_t)NN * HD, cross, NN, NN, HD, NN, 0, 0,
        nullptr, nullptr);

    // SPD loss (packed) + cosine recon-loss blocks (y==8)
    k_spd2<<<dim3(NN, 9), dim3(256), 0, stream>>>(
        pab, Svec, Qvec, cross, spd_g, spd_be, spd_W2, spd_b2, spd_matrix, spd_part,
        eo, dec_b2, mask_idx, feat_text, feat_image, rec_part);

    // final loss reduce
    k_out<<<dim3(1), dim3(256), 0, stream>>>(rec_part, spd_part, (float*)d_out);
}